// Round 3
// baseline (1188.261 us; speedup 1.0000x reference)
//
#include <hip/hip_runtime.h>

// GCN 3-layer encoder for MI355X.
// init -> degree atomics -> dinv -> CSR-bucket fill -> [gemm -> aggregate] x3
// Workspace: cnt[N] int, dinv[N] f32, EW[N*cap] int2 (src, norm-bits),
// bufH[N*128] f32, bufA[N*128] f32. cap from ws_size (<=64).

__global__ __launch_bounds__(256) void k_init(float* deg, int* cnt, int N) {
    int i = blockIdx.x * 256 + threadIdx.x;
    if (i < N) { deg[i] = 1.0f; cnt[i] = 0; }  // 1.0 = self-loop weight
}

__global__ __launch_bounds__(256) void k_degree(const int* __restrict__ dst,
                                                const float* __restrict__ w,
                                                float* deg, int E) {
    int e = blockIdx.x * 256 + threadIdx.x;
    if (e < E) atomicAdd(&deg[dst[e]], w[e]);
}

__global__ __launch_bounds__(256) void k_dinv(float* deg, int N) {
    int i = blockIdx.x * 256 + threadIdx.x;
    if (i < N) {
        float d = deg[i];
        deg[i] = (d > 0.f) ? (1.0f / sqrtf(d)) : 0.f;
    }
}

__global__ __launch_bounds__(256) void k_fill(const int* __restrict__ src,
                                              const int* __restrict__ dst,
                                              const float* __restrict__ w,
                                              const float* __restrict__ dinv,
                                              int* cnt, int2* __restrict__ EW,
                                              int E, int cap) {
    int e = blockIdx.x * 256 + threadIdx.x;
    if (e >= E) return;
    int s = src[e], t = dst[e];
    int k = atomicAdd(&cnt[t], 1);
    if (k < cap) {
        float nrm = dinv[s] * w[e] * dinv[t];
        EW[(size_t)t * cap + k] = make_int2(s, __float_as_int(nrm));
    }
}

// GEMM: H[N x DOUT] = X[N x 128] @ W[128 x DOUT].
// grid = (row tiles of 64, DOUT/64 col-halves). Block 256 thr = 4 waves.
// Each block stages a 128x64 W half in LDS (32 KB -> 5 blocks/CU, ~62% occ).
// Each wave: 16 rows x 64 cols (1 col/lane). X reads are row-broadcast
// float4 loads (L1-resident tile); W reads from LDS, 2-way bank (free).
template <int DOUT>
__global__ __launch_bounds__(256) void k_gemm(const float* __restrict__ X,
                                              const float* __restrict__ W,
                                              float* __restrict__ H, int N) {
    __shared__ float Ws[128 * 64];  // 32 KB
    const int colbase = blockIdx.y * 64;
    for (int idx = threadIdx.x; idx < 128 * 64; idx += 256) {
        int k = idx >> 6, c = idx & 63;
        Ws[idx] = W[k * DOUT + colbase + c];
    }
    __syncthreads();

    const int lane = threadIdx.x & 63;
    const int g = threadIdx.x >> 6;
    const int row0 = blockIdx.x * 64 + g * 16;

    float acc[16];
#pragma unroll
    for (int i = 0; i < 16; i++) acc[i] = 0.f;

    int rcl[16];
#pragma unroll
    for (int i = 0; i < 16; i++) {
        int r = row0 + i;
        rcl[i] = (r < N) ? r : (N - 1);  // clamp loads, guard stores
    }

    const float4* X4 = reinterpret_cast<const float4*>(X);
    for (int k0 = 0; k0 < 128; k0 += 4) {
        float wv[4];
#pragma unroll
        for (int j = 0; j < 4; j++) wv[j] = Ws[(k0 + j) * 64 + lane];
#pragma unroll
        for (int i = 0; i < 16; i++) {
            float4 xv = X4[(size_t)rcl[i] * 32 + (k0 >> 2)];
            acc[i] = fmaf(xv.x, wv[0], acc[i]);
            acc[i] = fmaf(xv.y, wv[1], acc[i]);
            acc[i] = fmaf(xv.z, wv[2], acc[i]);
            acc[i] = fmaf(xv.w, wv[3], acc[i]);
        }
    }

#pragma unroll
    for (int i = 0; i < 16; i++) {
        int r = row0 + i;
        if (r < N) H[(size_t)r * DOUT + colbase + lane] = acc[i];
    }
}

// Aggregate: out[i] = sum_{e: dst=i} norm_e * h[src_e] + dinv[i]^2 * h[i] + b
// One wave per node. Edge meta preloaded per-lane; broadcast via readlane
// (uniform k -> scalar src/norm -> scalar-base addressing). Edge loop
// unrolled x4 for 4 gathers in flight.
#define RL(v, k) __builtin_amdgcn_readlane((v), (k))

template <int DOUT, bool RELU>
__global__ __launch_bounds__(256) void k_agg(const float* __restrict__ H,
                                             const int2* __restrict__ EW,
                                             const int* __restrict__ cnt,
                                             const float* __restrict__ dinv,
                                             const float* __restrict__ bias,
                                             float* __restrict__ Out,
                                             int N, int cap) {
    int node = blockIdx.x * 4 + (threadIdx.x >> 6);
    if (node >= N) return;
    const int lane = threadIdx.x & 63;

    int c = cnt[node];  // wave-uniform
    c = (c < cap) ? c : cap;

    int2 meta = make_int2(0, 0);
    if (lane < c) meta = EW[(size_t)node * cap + lane];

    float d = dinv[node];
    float selfw = d * d;

    if constexpr (DOUT == 128) {
        const float2* H2 = reinterpret_cast<const float2*>(H);
        float2 hs = H2[(size_t)node * 64 + lane];
        float a0 = selfw * hs.x, a1 = selfw * hs.y;
        int k = 0;
        for (; k + 4 <= c; k += 4) {
            int s0 = RL(meta.x, k), s1 = RL(meta.x, k + 1);
            int s2 = RL(meta.x, k + 2), s3 = RL(meta.x, k + 3);
            float w0 = __int_as_float(RL(meta.y, k));
            float w1 = __int_as_float(RL(meta.y, k + 1));
            float w2 = __int_as_float(RL(meta.y, k + 2));
            float w3 = __int_as_float(RL(meta.y, k + 3));
            float2 h0 = H2[(size_t)s0 * 64 + lane];
            float2 h1 = H2[(size_t)s1 * 64 + lane];
            float2 h2 = H2[(size_t)s2 * 64 + lane];
            float2 h3 = H2[(size_t)s3 * 64 + lane];
            a0 = fmaf(w0, h0.x, a0); a1 = fmaf(w0, h0.y, a1);
            a0 = fmaf(w1, h1.x, a0); a1 = fmaf(w1, h1.y, a1);
            a0 = fmaf(w2, h2.x, a0); a1 = fmaf(w2, h2.y, a1);
            a0 = fmaf(w3, h3.x, a0); a1 = fmaf(w3, h3.y, a1);
        }
        for (; k < c; k++) {
            int s = RL(meta.x, k);
            float w = __int_as_float(RL(meta.y, k));
            float2 hv = H2[(size_t)s * 64 + lane];
            a0 = fmaf(w, hv.x, a0);
            a1 = fmaf(w, hv.y, a1);
        }
        float2 b = reinterpret_cast<const float2*>(bias)[lane];
        a0 += b.x; a1 += b.y;
        if (RELU) { a0 = fmaxf(a0, 0.f); a1 = fmaxf(a1, 0.f); }
        reinterpret_cast<float2*>(Out)[(size_t)node * 64 + lane] = make_float2(a0, a1);
    } else {  // DOUT == 64
        float a = selfw * H[(size_t)node * 64 + lane];
        int k = 0;
        for (; k + 4 <= c; k += 4) {
            int s0 = RL(meta.x, k), s1 = RL(meta.x, k + 1);
            int s2 = RL(meta.x, k + 2), s3 = RL(meta.x, k + 3);
            float w0 = __int_as_float(RL(meta.y, k));
            float w1 = __int_as_float(RL(meta.y, k + 1));
            float w2 = __int_as_float(RL(meta.y, k + 2));
            float w3 = __int_as_float(RL(meta.y, k + 3));
            float h0 = H[(size_t)s0 * 64 + lane];
            float h1 = H[(size_t)s1 * 64 + lane];
            float h2 = H[(size_t)s2 * 64 + lane];
            float h3 = H[(size_t)s3 * 64 + lane];
            a = fmaf(w0, h0, a); a = fmaf(w1, h1, a);
            a = fmaf(w2, h2, a); a = fmaf(w3, h3, a);
        }
        for (; k < c; k++) {
            int s = RL(meta.x, k);
            float w = __int_as_float(RL(meta.y, k));
            a = fmaf(w, H[(size_t)s * 64 + lane], a);
        }
        a += bias[lane];
        if (RELU) a = fmaxf(a, 0.f);
        Out[(size_t)node * 64 + lane] = a;
    }
}

extern "C" void kernel_launch(void* const* d_in, const int* in_sizes, int n_in,
                              void* d_out, int out_size, void* d_ws, size_t ws_size,
                              hipStream_t stream) {
    const int N = in_sizes[0] / 128;   // x is [N,128]
    const int E = in_sizes[2];         // edge_weight is [E]

    const float* x  = (const float*)d_in[0];
    const int*   ei = (const int*)d_in[1];   // [2,E]: row0=src, row1=dst
    const int*   src = ei;
    const int*   dst = ei + E;
    const float* ew  = (const float*)d_in[2];
    const float* W0 = (const float*)d_in[3];
    const float* b0 = (const float*)d_in[4];
    const float* W1 = (const float*)d_in[5];
    const float* b1 = (const float*)d_in[6];
    const float* W2 = (const float*)d_in[7];
    const float* b2 = (const float*)d_in[8];

    // Workspace carve; bucket capacity adapts so we never write past d_ws.
    size_t fixed = 2 * (((size_t)N * 4 + 255) & ~(size_t)255)
                 + 2 * (((size_t)N * 128 * 4 + 255) & ~(size_t)255)
                 + 1024;
    int cap = 64;
    if (ws_size > fixed) {
        size_t avail = (ws_size - fixed) / ((size_t)N * 8);
        if (avail < (size_t)cap) cap = (int)avail;
    } else {
        cap = 0;
    }

    char* p = (char*)d_ws;
    auto alloc = [&](size_t bytes) -> void* {
        void* r = (void*)p;
        p += (bytes + 255) & ~(size_t)255;
        return r;
    };
    int*   cnt  = (int*)alloc((size_t)N * 4);
    float* dinv = (float*)alloc((size_t)N * 4);
    int2*  EW   = (int2*)alloc((size_t)N * cap * 8);
    float* bufH = (float*)alloc((size_t)N * 128 * 4);
    float* bufA = (float*)alloc((size_t)N * 128 * 4);

    dim3 blk(256);
    dim3 gN((N + 255) / 256), gE((E + 255) / 256);
    dim3 gGemm128((N + 63) / 64, 2), gGemm64((N + 63) / 64, 1);
    dim3 gAgg((N + 3) / 4);

    // gcn_norm
    k_init<<<gN, blk, 0, stream>>>(dinv, cnt, N);
    k_degree<<<gE, blk, 0, stream>>>(dst, ew, dinv, E);
    k_dinv<<<gN, blk, 0, stream>>>(dinv, N);
    k_fill<<<gE, blk, 0, stream>>>(src, dst, ew, dinv, cnt, EW, E, cap);

    // layer 0
    k_gemm<128><<<gGemm128, blk, 0, stream>>>(x, W0, bufH, N);
    k_agg<128, true><<<gAgg, blk, 0, stream>>>(bufH, EW, cnt, dinv, b0, bufA, N, cap);

    // layer 1
    k_gemm<128><<<gGemm128, blk, 0, stream>>>(bufA, W1, bufH, N);
    k_agg<128, true><<<gAgg, blk, 0, stream>>>(bufH, EW, cnt, dinv, b1, bufA, N, cap);

    // layer 2 (no relu)
    k_gemm<64><<<gGemm64, blk, 0, stream>>>(bufA, W2, bufH, N);
    k_agg<64, false><<<gAgg, blk, 0, stream>>>(bufH, EW, cnt, dinv, b2,
                                               (float*)d_out, N, cap);
}

// Round 4
// 754.682 us; speedup vs baseline: 1.5745x; 1.5745x over previous
//
#include <hip/hip_runtime.h>

// GCN 3-layer encoder for MI355X.
// init -> degree atomics -> dinv -> CSR-bucket fill -> [gemm -> aggregate] x3
// Workspace: cnt[N] int, dinv[N] f32, EW[N*cap] int2 (src, norm-bits),
// bufH[N*128] f32, bufA[N*128] f32. cap from ws_size (<=64).

__global__ __launch_bounds__(256) void k_init(float* deg, int* cnt, int N) {
    int i = blockIdx.x * 256 + threadIdx.x;
    if (i < N) { deg[i] = 1.0f; cnt[i] = 0; }  // 1.0 = self-loop weight
}

__global__ __launch_bounds__(256) void k_degree(const int* __restrict__ dst,
                                                const float* __restrict__ w,
                                                float* deg, int E) {
    int e = blockIdx.x * 256 + threadIdx.x;
    if (e < E) atomicAdd(&deg[dst[e]], w[e]);
}

__global__ __launch_bounds__(256) void k_dinv(float* deg, int N) {
    int i = blockIdx.x * 256 + threadIdx.x;
    if (i < N) {
        float d = deg[i];
        deg[i] = (d > 0.f) ? (1.0f / sqrtf(d)) : 0.f;
    }
}

__global__ __launch_bounds__(256) void k_fill(const int* __restrict__ src,
                                              const int* __restrict__ dst,
                                              const float* __restrict__ w,
                                              const float* __restrict__ dinv,
                                              int* cnt, int2* __restrict__ EW,
                                              int E, int cap) {
    int e = blockIdx.x * 256 + threadIdx.x;
    if (e >= E) return;
    int s = src[e], t = dst[e];
    int k = atomicAdd(&cnt[t], 1);
    if (k < cap) {
        float nrm = dinv[s] * w[e] * dinv[t];
        EW[(size_t)t * cap + k] = make_int2(s, __float_as_int(nrm));
    }
}

// Tiled fp32 GEMM: H[N x BN] = X[N x 128] @ W[128 x BN], BN in {128, 64}.
// Block 256 thr: tile 128 rows x BN cols, BK=16, LDS Xs (k-major, transposed
// on store) + Ws. Per-thread 8x(BN/16) register tile. Thread rows/cols are
// {4g..4g+3} u {64+4g..+3} so every ds_read_b128 across a wave covers 64
// contiguous words -> 2 addrs/bank -> conflict-free. Next tile's global
// loads are register-prefetched under compute.
template <int BN>
__global__ __launch_bounds__(256, 4) void k_gemm(const float* __restrict__ X,
                                                 const float* __restrict__ W,
                                                 float* __restrict__ H, int N) {
    __shared__ float Xs[16][128];
    __shared__ float Ws[16][BN];

    const int tid = threadIdx.x;
    const int g = tid & 15;   // row group
    const int c = tid >> 4;   // col group
    const int rb = blockIdx.x * 128;

    // X staging: thread covers row (tid&127), ks [skh*8, skh*8+8)
    const int srow = tid & 127;
    const int skh = tid >> 7;
    const size_t xrow = (size_t)((rb + srow < N) ? (rb + srow) : (N - 1));

    constexpr int CPT = BN / 16;  // cols per thread: 8 or 4

    float acc[8][CPT];
#pragma unroll
    for (int i = 0; i < 8; i++)
#pragma unroll
        for (int j = 0; j < CPT; j++) acc[i][j] = 0.f;

    float4 x0, x1, w0, w1;
    auto loadX = [&](int kb) {
        const float* p = X + xrow * 128 + kb + skh * 8;
        x0 = *(const float4*)p;
        x1 = *(const float4*)(p + 4);
    };
    auto loadW = [&](int kb) {
        if constexpr (BN == 128) {
            int wrow = tid >> 5, wcol = (tid & 31) * 4;
            w0 = *(const float4*)(W + (kb + wrow) * BN + wcol);
            w1 = *(const float4*)(W + (kb + wrow + 8) * BN + wcol);
        } else {
            int wrow = tid >> 4, wcol = (tid & 15) * 4;
            w0 = *(const float4*)(W + (kb + wrow) * BN + wcol);
        }
    };

    loadX(0);
    loadW(0);

    for (int kt = 0; kt < 8; kt++) {
        // stage registers -> LDS
        Xs[skh * 8 + 0][srow] = x0.x;
        Xs[skh * 8 + 1][srow] = x0.y;
        Xs[skh * 8 + 2][srow] = x0.z;
        Xs[skh * 8 + 3][srow] = x0.w;
        Xs[skh * 8 + 4][srow] = x1.x;
        Xs[skh * 8 + 5][srow] = x1.y;
        Xs[skh * 8 + 6][srow] = x1.z;
        Xs[skh * 8 + 7][srow] = x1.w;
        if constexpr (BN == 128) {
            int wrow = tid >> 5, wcol = (tid & 31) * 4;
            *(float4*)&Ws[wrow][wcol] = w0;
            *(float4*)&Ws[wrow + 8][wcol] = w1;
        } else {
            int wrow = tid >> 4, wcol = (tid & 15) * 4;
            *(float4*)&Ws[wrow][wcol] = w0;
        }
        __syncthreads();

        if (kt < 7) { loadX((kt + 1) * 16); loadW((kt + 1) * 16); }

#pragma unroll
        for (int k = 0; k < 16; k++) {
            float4 a0 = *(const float4*)&Xs[k][4 * g];
            float4 a1 = *(const float4*)&Xs[k][64 + 4 * g];
            float av[8] = {a0.x, a0.y, a0.z, a0.w, a1.x, a1.y, a1.z, a1.w};
            float4 b0 = *(const float4*)&Ws[k][4 * c];
            float bv[CPT];
            bv[0] = b0.x; bv[1] = b0.y; bv[2] = b0.z; bv[3] = b0.w;
            if constexpr (BN == 128) {
                float4 b1 = *(const float4*)&Ws[k][64 + 4 * c];
                bv[4] = b1.x; bv[5] = b1.y; bv[6] = b1.z; bv[7] = b1.w;
            }
#pragma unroll
            for (int i = 0; i < 8; i++)
#pragma unroll
                for (int j = 0; j < CPT; j++)
                    acc[i][j] = fmaf(av[i], bv[j], acc[i][j]);
        }
        __syncthreads();
    }

    // epilogue: rows {4g+i, 64+4g+i}, cols {4c+j, 64+4c+j}
#pragma unroll
    for (int i = 0; i < 8; i++) {
        int r = rb + ((i < 4) ? (4 * g + i) : (64 + 4 * g + i - 4));
        if (r < N) {
            float4 o0 = make_float4(acc[i][0], acc[i][1], acc[i][2], acc[i][3]);
            *(float4*)&H[(size_t)r * BN + 4 * c] = o0;
            if constexpr (BN == 128) {
                float4 o1 = make_float4(acc[i][4], acc[i][5], acc[i][6], acc[i][7]);
                *(float4*)&H[(size_t)r * BN + 64 + 4 * c] = o1;
            }
        }
    }
}

// Aggregate: out[i] = sum_{e: dst=i} norm_e * h[src_e] + dinv[i]^2 * h[i] + b
// One wave per node. Edge meta preloaded per-lane; broadcast via readlane.
// Edge loop unrolled x8 for 8 gathers in flight (H is ~L3-resident).
#define RL(v, k) __builtin_amdgcn_readlane((v), (k))

template <int DOUT, bool RELU>
__global__ __launch_bounds__(256) void k_agg(const float* __restrict__ H,
                                             const int2* __restrict__ EW,
                                             const int* __restrict__ cnt,
                                             const float* __restrict__ dinv,
                                             const float* __restrict__ bias,
                                             float* __restrict__ Out,
                                             int N, int cap) {
    int node = blockIdx.x * 4 + (threadIdx.x >> 6);
    if (node >= N) return;
    const int lane = threadIdx.x & 63;

    int c = cnt[node];  // wave-uniform
    c = (c < cap) ? c : cap;

    int2 meta = make_int2(0, 0);
    if (lane < c) meta = EW[(size_t)node * cap + lane];

    float d = dinv[node];
    float selfw = d * d;

    if constexpr (DOUT == 128) {
        const float2* H2 = reinterpret_cast<const float2*>(H);
        float2 hs = H2[(size_t)node * 64 + lane];
        float a0 = selfw * hs.x, a1 = selfw * hs.y;
        int k = 0;
        for (; k + 8 <= c; k += 8) {
            float2 hv[8]; float w[8];
#pragma unroll
            for (int u = 0; u < 8; u++) {
                int s = RL(meta.x, k + u);
                w[u] = __int_as_float(RL(meta.y, k + u));
                hv[u] = H2[(size_t)s * 64 + lane];
            }
#pragma unroll
            for (int u = 0; u < 8; u++) {
                a0 = fmaf(w[u], hv[u].x, a0);
                a1 = fmaf(w[u], hv[u].y, a1);
            }
        }
        for (; k + 4 <= c; k += 4) {
            float2 hv[4]; float w[4];
#pragma unroll
            for (int u = 0; u < 4; u++) {
                int s = RL(meta.x, k + u);
                w[u] = __int_as_float(RL(meta.y, k + u));
                hv[u] = H2[(size_t)s * 64 + lane];
            }
#pragma unroll
            for (int u = 0; u < 4; u++) {
                a0 = fmaf(w[u], hv[u].x, a0);
                a1 = fmaf(w[u], hv[u].y, a1);
            }
        }
        for (; k < c; k++) {
            int s = RL(meta.x, k);
            float w = __int_as_float(RL(meta.y, k));
            float2 hv = H2[(size_t)s * 64 + lane];
            a0 = fmaf(w, hv.x, a0);
            a1 = fmaf(w, hv.y, a1);
        }
        float2 b = reinterpret_cast<const float2*>(bias)[lane];
        a0 += b.x; a1 += b.y;
        if (RELU) { a0 = fmaxf(a0, 0.f); a1 = fmaxf(a1, 0.f); }
        reinterpret_cast<float2*>(Out)[(size_t)node * 64 + lane] = make_float2(a0, a1);
    } else {  // DOUT == 64
        float a = selfw * H[(size_t)node * 64 + lane];
        int k = 0;
        for (; k + 8 <= c; k += 8) {
            float hv[8]; float w[8];
#pragma unroll
            for (int u = 0; u < 8; u++) {
                int s = RL(meta.x, k + u);
                w[u] = __int_as_float(RL(meta.y, k + u));
                hv[u] = H[(size_t)s * 64 + lane];
            }
#pragma unroll
            for (int u = 0; u < 8; u++) a = fmaf(w[u], hv[u], a);
        }
        for (; k < c; k++) {
            int s = RL(meta.x, k);
            float w = __int_as_float(RL(meta.y, k));
            a = fmaf(w, H[(size_t)s * 64 + lane], a);
        }
        a += bias[lane];
        if (RELU) a = fmaxf(a, 0.f);
        Out[(size_t)node * 64 + lane] = a;
    }
}

extern "C" void kernel_launch(void* const* d_in, const int* in_sizes, int n_in,
                              void* d_out, int out_size, void* d_ws, size_t ws_size,
                              hipStream_t stream) {
    const int N = in_sizes[0] / 128;   // x is [N,128]
    const int E = in_sizes[2];         // edge_weight is [E]

    const float* x  = (const float*)d_in[0];
    const int*   ei = (const int*)d_in[1];   // [2,E]: row0=src, row1=dst
    const int*   src = ei;
    const int*   dst = ei + E;
    const float* ew  = (const float*)d_in[2];
    const float* W0 = (const float*)d_in[3];
    const float* b0 = (const float*)d_in[4];
    const float* W1 = (const float*)d_in[5];
    const float* b1 = (const float*)d_in[6];
    const float* W2 = (const float*)d_in[7];
    const float* b2 = (const float*)d_in[8];

    // Workspace carve; bucket capacity adapts so we never write past d_ws.
    size_t fixed = 2 * (((size_t)N * 4 + 255) & ~(size_t)255)
                 + 2 * (((size_t)N * 128 * 4 + 255) & ~(size_t)255)
                 + 1024;
    int cap = 64;
    if (ws_size > fixed) {
        size_t avail = (ws_size - fixed) / ((size_t)N * 8);
        if (avail < (size_t)cap) cap = (int)avail;
    } else {
        cap = 0;
    }

    char* p = (char*)d_ws;
    auto alloc = [&](size_t bytes) -> void* {
        void* r = (void*)p;
        p += (bytes + 255) & ~(size_t)255;
        return r;
    };
    int*   cnt  = (int*)alloc((size_t)N * 4);
    float* dinv = (float*)alloc((size_t)N * 4);
    int2*  EW   = (int2*)alloc((size_t)N * cap * 8);
    float* bufH = (float*)alloc((size_t)N * 128 * 4);
    float* bufA = (float*)alloc((size_t)N * 128 * 4);

    dim3 blk(256);
    dim3 gN((N + 255) / 256), gE((E + 255) / 256);
    dim3 gGemm((N + 127) / 128);
    dim3 gAgg((N + 3) / 4);

    // gcn_norm
    k_init<<<gN, blk, 0, stream>>>(dinv, cnt, N);
    k_degree<<<gE, blk, 0, stream>>>(dst, ew, dinv, E);
    k_dinv<<<gN, blk, 0, stream>>>(dinv, N);
    k_fill<<<gE, blk, 0, stream>>>(src, dst, ew, dinv, cnt, EW, E, cap);

    // layer 0
    k_gemm<128><<<gGemm, blk, 0, stream>>>(x, W0, bufH, N);
    k_agg<128, true><<<gAgg, blk, 0, stream>>>(bufH, EW, cnt, dinv, b0, bufA, N, cap);

    // layer 1
    k_gemm<128><<<gGemm, blk, 0, stream>>>(bufA, W1, bufH, N);
    k_agg<128, true><<<gAgg, blk, 0, stream>>>(bufH, EW, cnt, dinv, b1, bufA, N, cap);

    // layer 2 (no relu)
    k_gemm<64><<<gGemm, blk, 0, stream>>>(bufA, W2, bufH, N);
    k_agg<64, false><<<gAgg, blk, 0, stream>>>(bufH, EW, cnt, dinv, b2,
                                               (float*)d_out, N, cap);
}

// Round 5
// 612.219 us; speedup vs baseline: 1.9409x; 1.2327x over previous
//
#include <hip/hip_runtime.h>
#include <hip/hip_fp16.h>

// GCN 3-layer encoder for MI355X.
// init -> degree atomics -> dinv -> CSR-bucket fill -> [gemm -> aggregate] x3
// H (post-GEMM features, gathered ~17x per row) is stored fp16 to halve the
// random-gather HBM traffic (the round-4 bottleneck: 406 MB L2-miss/layer,
// already at the temporal-reuse bound for a random graph). Accumulation fp32.
// Workspace: cnt[N] int, dinv[N] f32, EW[N*cap] int2 (src, norm-bits),
// bufH[N*128] fp16, bufA[N*128] f32. cap from ws_size (<=64).

struct alignas(8) half4 { __half2 a, b; };

__global__ __launch_bounds__(256) void k_init(float* deg, int* cnt, int N) {
    int i = blockIdx.x * 256 + threadIdx.x;
    if (i < N) { deg[i] = 1.0f; cnt[i] = 0; }  // 1.0 = self-loop weight
}

__global__ __launch_bounds__(256) void k_degree(const int* __restrict__ dst,
                                                const float* __restrict__ w,
                                                float* deg, int E) {
    int e = blockIdx.x * 256 + threadIdx.x;
    if (e < E) atomicAdd(&deg[dst[e]], w[e]);
}

__global__ __launch_bounds__(256) void k_dinv(float* deg, int N) {
    int i = blockIdx.x * 256 + threadIdx.x;
    if (i < N) {
        float d = deg[i];
        deg[i] = (d > 0.f) ? (1.0f / sqrtf(d)) : 0.f;
    }
}

__global__ __launch_bounds__(256) void k_fill(const int* __restrict__ src,
                                              const int* __restrict__ dst,
                                              const float* __restrict__ w,
                                              const float* __restrict__ dinv,
                                              int* cnt, int2* __restrict__ EW,
                                              int E, int cap) {
    int e = blockIdx.x * 256 + threadIdx.x;
    if (e >= E) return;
    int s = src[e], t = dst[e];
    int k = atomicAdd(&cnt[t], 1);
    if (k < cap) {
        float nrm = dinv[s] * w[e] * dinv[t];
        EW[(size_t)t * cap + k] = make_int2(s, __float_as_int(nrm));
    }
}

// Tiled fp32 GEMM: H[N x BN] = X[N x 128] @ W[128 x BN], BN in {128, 64}.
// Output stored fp16. Block 256 thr: 128-row x BN-col tile, BK=16, LDS
// staging with register prefetch. Per-thread 8x(BN/16) register tile; thread
// rows/cols {4g..4g+3} u {64+4g..+3} keep ds_read_b128 2-way-bank (free).
template <int BN>
__global__ __launch_bounds__(256, 4) void k_gemm(const float* __restrict__ X,
                                                 const float* __restrict__ W,
                                                 __half* __restrict__ H, int N) {
    __shared__ float Xs[16][128];
    __shared__ float Ws[16][BN];

    const int tid = threadIdx.x;
    const int g = tid & 15;   // row group
    const int c = tid >> 4;   // col group
    const int rb = blockIdx.x * 128;

    const int srow = tid & 127;
    const int skh = tid >> 7;
    const size_t xrow = (size_t)((rb + srow < N) ? (rb + srow) : (N - 1));

    constexpr int CPT = BN / 16;  // cols per thread: 8 or 4

    float acc[8][CPT];
#pragma unroll
    for (int i = 0; i < 8; i++)
#pragma unroll
        for (int j = 0; j < CPT; j++) acc[i][j] = 0.f;

    float4 x0, x1, w0, w1;
    auto loadX = [&](int kb) {
        const float* p = X + xrow * 128 + kb + skh * 8;
        x0 = *(const float4*)p;
        x1 = *(const float4*)(p + 4);
    };
    auto loadW = [&](int kb) {
        if constexpr (BN == 128) {
            int wrow = tid >> 5, wcol = (tid & 31) * 4;
            w0 = *(const float4*)(W + (kb + wrow) * BN + wcol);
            w1 = *(const float4*)(W + (kb + wrow + 8) * BN + wcol);
        } else {
            int wrow = tid >> 4, wcol = (tid & 15) * 4;
            w0 = *(const float4*)(W + (kb + wrow) * BN + wcol);
        }
    };

    loadX(0);
    loadW(0);

    for (int kt = 0; kt < 8; kt++) {
        Xs[skh * 8 + 0][srow] = x0.x;
        Xs[skh * 8 + 1][srow] = x0.y;
        Xs[skh * 8 + 2][srow] = x0.z;
        Xs[skh * 8 + 3][srow] = x0.w;
        Xs[skh * 8 + 4][srow] = x1.x;
        Xs[skh * 8 + 5][srow] = x1.y;
        Xs[skh * 8 + 6][srow] = x1.z;
        Xs[skh * 8 + 7][srow] = x1.w;
        if constexpr (BN == 128) {
            int wrow = tid >> 5, wcol = (tid & 31) * 4;
            *(float4*)&Ws[wrow][wcol] = w0;
            *(float4*)&Ws[wrow + 8][wcol] = w1;
        } else {
            int wrow = tid >> 4, wcol = (tid & 15) * 4;
            *(float4*)&Ws[wrow][wcol] = w0;
        }
        __syncthreads();

        if (kt < 7) { loadX((kt + 1) * 16); loadW((kt + 1) * 16); }

#pragma unroll
        for (int k = 0; k < 16; k++) {
            float4 a0 = *(const float4*)&Xs[k][4 * g];
            float4 a1 = *(const float4*)&Xs[k][64 + 4 * g];
            float av[8] = {a0.x, a0.y, a0.z, a0.w, a1.x, a1.y, a1.z, a1.w};
            float4 b0 = *(const float4*)&Ws[k][4 * c];
            float bv[CPT];
            bv[0] = b0.x; bv[1] = b0.y; bv[2] = b0.z; bv[3] = b0.w;
            if constexpr (BN == 128) {
                float4 b1 = *(const float4*)&Ws[k][64 + 4 * c];
                bv[4] = b1.x; bv[5] = b1.y; bv[6] = b1.z; bv[7] = b1.w;
            }
#pragma unroll
            for (int i = 0; i < 8; i++)
#pragma unroll
                for (int j = 0; j < CPT; j++)
                    acc[i][j] = fmaf(av[i], bv[j], acc[i][j]);
        }
        __syncthreads();
    }

    // epilogue: fp32 acc -> fp16 store. rows {4g+i, 64+4g+i-4}, cols 4c(+64).
#pragma unroll
    for (int i = 0; i < 8; i++) {
        int r = rb + ((i < 4) ? (4 * g + i) : (64 + 4 * g + i - 4));
        if (r < N) {
            half4 o0;
            o0.a = __floats2half2_rn(acc[i][0], acc[i][1]);
            o0.b = __floats2half2_rn(acc[i][2], acc[i][3]);
            *(half4*)&H[(size_t)r * BN + 4 * c] = o0;
            if constexpr (BN == 128) {
                half4 o1;
                o1.a = __floats2half2_rn(acc[i][4], acc[i][5]);
                o1.b = __floats2half2_rn(acc[i][6], acc[i][7]);
                *(half4*)&H[(size_t)r * BN + 64 + 4 * c] = o1;
            }
        }
    }
}

// Aggregate: out[i] = sum_{e: dst=i} norm_e * h[src_e] + dinv[i]^2 * h[i] + b
// One wave per node; H is fp16 (256B/row @128, 128B/row @64), fp32 accum.
// Edge meta per-lane, broadcast via readlane; unroll x8 gathers in flight.
#define RL(v, k) __builtin_amdgcn_readlane((v), (k))

template <int DOUT, bool RELU>
__global__ __launch_bounds__(256) void k_agg(const __half* __restrict__ H,
                                             const int2* __restrict__ EW,
                                             const int* __restrict__ cnt,
                                             const float* __restrict__ dinv,
                                             const float* __restrict__ bias,
                                             float* __restrict__ Out,
                                             int N, int cap) {
    int node = blockIdx.x * 4 + (threadIdx.x >> 6);
    if (node >= N) return;
    const int lane = threadIdx.x & 63;

    int c = cnt[node];  // wave-uniform
    c = (c < cap) ? c : cap;

    int2 meta = make_int2(0, 0);
    if (lane < c) meta = EW[(size_t)node * cap + lane];

    float d = dinv[node];
    float selfw = d * d;

    if constexpr (DOUT == 128) {
        const __half2* H2 = reinterpret_cast<const __half2*>(H);
        float2 hs = __half22float2(H2[(size_t)node * 64 + lane]);
        float a0 = selfw * hs.x, a1 = selfw * hs.y;
        int k = 0;
        for (; k + 8 <= c; k += 8) {
            __half2 hr[8]; float w[8];
#pragma unroll
            for (int u = 0; u < 8; u++) {
                int s = RL(meta.x, k + u);
                w[u] = __int_as_float(RL(meta.y, k + u));
                hr[u] = H2[(size_t)s * 64 + lane];
            }
#pragma unroll
            for (int u = 0; u < 8; u++) {
                float2 hv = __half22float2(hr[u]);
                a0 = fmaf(w[u], hv.x, a0);
                a1 = fmaf(w[u], hv.y, a1);
            }
        }
        for (; k + 4 <= c; k += 4) {
            __half2 hr[4]; float w[4];
#pragma unroll
            for (int u = 0; u < 4; u++) {
                int s = RL(meta.x, k + u);
                w[u] = __int_as_float(RL(meta.y, k + u));
                hr[u] = H2[(size_t)s * 64 + lane];
            }
#pragma unroll
            for (int u = 0; u < 4; u++) {
                float2 hv = __half22float2(hr[u]);
                a0 = fmaf(w[u], hv.x, a0);
                a1 = fmaf(w[u], hv.y, a1);
            }
        }
        for (; k < c; k++) {
            int s = RL(meta.x, k);
            float w = __int_as_float(RL(meta.y, k));
            float2 hv = __half22float2(H2[(size_t)s * 64 + lane]);
            a0 = fmaf(w, hv.x, a0);
            a1 = fmaf(w, hv.y, a1);
        }
        float2 b = reinterpret_cast<const float2*>(bias)[lane];
        a0 += b.x; a1 += b.y;
        if (RELU) { a0 = fmaxf(a0, 0.f); a1 = fmaxf(a1, 0.f); }
        reinterpret_cast<float2*>(Out)[(size_t)node * 64 + lane] = make_float2(a0, a1);
    } else {  // DOUT == 64
        float a = selfw * __half2float(H[(size_t)node * 64 + lane]);
        int k = 0;
        for (; k + 8 <= c; k += 8) {
            __half hr[8]; float w[8];
#pragma unroll
            for (int u = 0; u < 8; u++) {
                int s = RL(meta.x, k + u);
                w[u] = __int_as_float(RL(meta.y, k + u));
                hr[u] = H[(size_t)s * 64 + lane];
            }
#pragma unroll
            for (int u = 0; u < 8; u++) a = fmaf(w[u], __half2float(hr[u]), a);
        }
        for (; k < c; k++) {
            int s = RL(meta.x, k);
            float w = __int_as_float(RL(meta.y, k));
            a = fmaf(w, __half2float(H[(size_t)s * 64 + lane]), a);
        }
        a += bias[lane];
        if (RELU) a = fmaxf(a, 0.f);
        Out[(size_t)node * 64 + lane] = a;
    }
}

extern "C" void kernel_launch(void* const* d_in, const int* in_sizes, int n_in,
                              void* d_out, int out_size, void* d_ws, size_t ws_size,
                              hipStream_t stream) {
    const int N = in_sizes[0] / 128;   // x is [N,128]
    const int E = in_sizes[2];         // edge_weight is [E]

    const float* x  = (const float*)d_in[0];
    const int*   ei = (const int*)d_in[1];   // [2,E]: row0=src, row1=dst
    const int*   src = ei;
    const int*   dst = ei + E;
    const float* ew  = (const float*)d_in[2];
    const float* W0 = (const float*)d_in[3];
    const float* b0 = (const float*)d_in[4];
    const float* W1 = (const float*)d_in[5];
    const float* b1 = (const float*)d_in[6];
    const float* W2 = (const float*)d_in[7];
    const float* b2 = (const float*)d_in[8];

    // Workspace carve; bucket capacity adapts so we never write past d_ws.
    size_t fixed = 2 * (((size_t)N * 4 + 255) & ~(size_t)255)       // cnt, dinv
                 + (((size_t)N * 128 * 2 + 255) & ~(size_t)255)     // bufH fp16
                 + (((size_t)N * 128 * 4 + 255) & ~(size_t)255)     // bufA fp32
                 + 1024;
    int cap = 64;
    if (ws_size > fixed) {
        size_t avail = (ws_size - fixed) / ((size_t)N * 8);
        if (avail < (size_t)cap) cap = (int)avail;
    } else {
        cap = 0;
    }

    char* p = (char*)d_ws;
    auto alloc = [&](size_t bytes) -> void* {
        void* r = (void*)p;
        p += (bytes + 255) & ~(size_t)255;
        return r;
    };
    int*    cnt  = (int*)alloc((size_t)N * 4);
    float*  dinv = (float*)alloc((size_t)N * 4);
    int2*   EW   = (int2*)alloc((size_t)N * cap * 8);
    __half* bufH = (__half*)alloc((size_t)N * 128 * 2);
    float*  bufA = (float*)alloc((size_t)N * 128 * 4);

    dim3 blk(256);
    dim3 gN((N + 255) / 256), gE((E + 255) / 256);
    dim3 gGemm((N + 127) / 128);
    dim3 gAgg((N + 3) / 4);

    // gcn_norm
    k_init<<<gN, blk, 0, stream>>>(dinv, cnt, N);
    k_degree<<<gE, blk, 0, stream>>>(dst, ew, dinv, E);
    k_dinv<<<gN, blk, 0, stream>>>(dinv, N);
    k_fill<<<gE, blk, 0, stream>>>(src, dst, ew, dinv, cnt, EW, E, cap);

    // layer 0
    k_gemm<128><<<gGemm, blk, 0, stream>>>(x, W0, bufH, N);
    k_agg<128, true><<<gAgg, blk, 0, stream>>>(bufH, EW, cnt, dinv, b0, bufA, N, cap);

    // layer 1
    k_gemm<128><<<gGemm, blk, 0, stream>>>(bufA, W1, bufH, N);
    k_agg<128, true><<<gAgg, blk, 0, stream>>>(bufH, EW, cnt, dinv, b1, bufA, N, cap);

    // layer 2 (no relu)
    k_gemm<64><<<gGemm, blk, 0, stream>>>(bufA, W2, bufH, N);
    k_agg<64, false><<<gAgg, blk, 0, stream>>>(bufH, EW, cnt, dinv, b2,
                                               (float*)d_out, N, cap);
}

// Round 6
// 611.325 us; speedup vs baseline: 1.9437x; 1.0015x over previous
//
#include <hip/hip_runtime.h>
#include <hip/hip_fp16.h>

// GCN 3-layer encoder for MI355X.
// Norm pipeline folds dinv into H: Hs[i] = dinv[i]*h[i] (fp16), EW holds raw
// edge weight, agg computes out[t] = dinv[t]*(sum w*Hs[s] + Hs[t]) + b.
// -> edge build pass needs NO per-edge dinv gathers and merges degree+fill.
// init -> build (deg atomic + cnt atomic + EW store) -> dinv
//      -> [gemm(xW, scale dinv) -> aggregate] x3
// Workspace: nm[N]{deg,cnt}, dinv[N] f32, EW[N*cap] int2 (src, w-bits),
// bufH[N*128] fp16, bufA[N*128] f32. cap from ws_size (<=64).

struct alignas(8) half4 { __half2 a, b; };
struct alignas(8) NodeMeta { float deg; int cnt; };

__global__ __launch_bounds__(256) void k_init(NodeMeta* nm, int N) {
    int i = blockIdx.x * 256 + threadIdx.x;
    if (i < N) { nm[i].deg = 1.0f; nm[i].cnt = 0; }  // 1.0 = self-loop weight
}

// One pass over edges: degree sum + slot assignment + EW store. Both atomics
// hit the same 8B NodeMeta -> same L2 line. No gathers.
__global__ __launch_bounds__(256) void k_build(const int* __restrict__ src,
                                               const int* __restrict__ dst,
                                               const float* __restrict__ w,
                                               NodeMeta* nm, int2* __restrict__ EW,
                                               int E, int cap) {
    int e = blockIdx.x * 256 + threadIdx.x;
    if (e >= E) return;
    int s = src[e], t = dst[e];
    float we = w[e];
    atomicAdd(&nm[t].deg, we);
    int k = atomicAdd(&nm[t].cnt, 1);
    if (k < cap) EW[(size_t)t * cap + k] = make_int2(s, __float_as_int(we));
}

__global__ __launch_bounds__(256) void k_dinv(const NodeMeta* __restrict__ nm,
                                              float* __restrict__ dinv, int N) {
    int i = blockIdx.x * 256 + threadIdx.x;
    if (i < N) {
        float d = nm[i].deg;  // >= 1.0 (self-loop), so always > 0
        dinv[i] = 1.0f / sqrtf(d);
    }
}

// Tiled fp32 GEMM: H[N x BN] = dinv[r] * (X[N x 128] @ W[128 x BN]), fp16 out.
// Block 256 thr: 128-row x BN-col tile, BK=16, LDS staging with register
// prefetch. Per-thread 8x(BN/16) register tile; thread rows/cols
// {4g..4g+3} u {64+4g..+3} keep ds_read_b128 2-way-bank (free).
template <int BN>
__global__ __launch_bounds__(256, 4) void k_gemm(const float* __restrict__ X,
                                                 const float* __restrict__ W,
                                                 const float* __restrict__ dinv,
                                                 __half* __restrict__ H, int N) {
    __shared__ float Xs[16][128];
    __shared__ float Ws[16][BN];

    const int tid = threadIdx.x;
    const int g = tid & 15;   // row group
    const int c = tid >> 4;   // col group
    const int rb = blockIdx.x * 128;

    const int srow = tid & 127;
    const int skh = tid >> 7;
    const size_t xrow = (size_t)((rb + srow < N) ? (rb + srow) : (N - 1));

    constexpr int CPT = BN / 16;  // cols per thread: 8 or 4

    float acc[8][CPT];
#pragma unroll
    for (int i = 0; i < 8; i++)
#pragma unroll
        for (int j = 0; j < CPT; j++) acc[i][j] = 0.f;

    float4 x0, x1, w0, w1;
    auto loadX = [&](int kb) {
        const float* p = X + xrow * 128 + kb + skh * 8;
        x0 = *(const float4*)p;
        x1 = *(const float4*)(p + 4);
    };
    auto loadW = [&](int kb) {
        if constexpr (BN == 128) {
            int wrow = tid >> 5, wcol = (tid & 31) * 4;
            w0 = *(const float4*)(W + (kb + wrow) * BN + wcol);
            w1 = *(const float4*)(W + (kb + wrow + 8) * BN + wcol);
        } else {
            int wrow = tid >> 4, wcol = (tid & 15) * 4;
            w0 = *(const float4*)(W + (kb + wrow) * BN + wcol);
        }
    };

    loadX(0);
    loadW(0);

    for (int kt = 0; kt < 8; kt++) {
        Xs[skh * 8 + 0][srow] = x0.x;
        Xs[skh * 8 + 1][srow] = x0.y;
        Xs[skh * 8 + 2][srow] = x0.z;
        Xs[skh * 8 + 3][srow] = x0.w;
        Xs[skh * 8 + 4][srow] = x1.x;
        Xs[skh * 8 + 5][srow] = x1.y;
        Xs[skh * 8 + 6][srow] = x1.z;
        Xs[skh * 8 + 7][srow] = x1.w;
        if constexpr (BN == 128) {
            int wrow = tid >> 5, wcol = (tid & 31) * 4;
            *(float4*)&Ws[wrow][wcol] = w0;
            *(float4*)&Ws[wrow + 8][wcol] = w1;
        } else {
            int wrow = tid >> 4, wcol = (tid & 15) * 4;
            *(float4*)&Ws[wrow][wcol] = w0;
        }
        __syncthreads();

        if (kt < 7) { loadX((kt + 1) * 16); loadW((kt + 1) * 16); }

#pragma unroll
        for (int k = 0; k < 16; k++) {
            float4 a0 = *(const float4*)&Xs[k][4 * g];
            float4 a1 = *(const float4*)&Xs[k][64 + 4 * g];
            float av[8] = {a0.x, a0.y, a0.z, a0.w, a1.x, a1.y, a1.z, a1.w};
            float4 b0 = *(const float4*)&Ws[k][4 * c];
            float bv[CPT];
            bv[0] = b0.x; bv[1] = b0.y; bv[2] = b0.z; bv[3] = b0.w;
            if constexpr (BN == 128) {
                float4 b1 = *(const float4*)&Ws[k][64 + 4 * c];
                bv[4] = b1.x; bv[5] = b1.y; bv[6] = b1.z; bv[7] = b1.w;
            }
#pragma unroll
            for (int i = 0; i < 8; i++)
#pragma unroll
                for (int j = 0; j < CPT; j++)
                    acc[i][j] = fmaf(av[i], bv[j], acc[i][j]);
        }
        __syncthreads();
    }

    // epilogue: scale by dinv[r], fp32 -> fp16 store.
#pragma unroll
    for (int i = 0; i < 8; i++) {
        int r = rb + ((i < 4) ? (4 * g + i) : (64 + 4 * g + i - 4));
        if (r < N) {
            float sc = dinv[r];
            half4 o0;
            o0.a = __floats2half2_rn(sc * acc[i][0], sc * acc[i][1]);
            o0.b = __floats2half2_rn(sc * acc[i][2], sc * acc[i][3]);
            *(half4*)&H[(size_t)r * BN + 4 * c] = o0;
            if constexpr (BN == 128) {
                half4 o1;
                o1.a = __floats2half2_rn(sc * acc[i][4], sc * acc[i][5]);
                o1.b = __floats2half2_rn(sc * acc[i][6], sc * acc[i][7]);
                *(half4*)&H[(size_t)r * BN + 64 + 4 * c] = o1;
            }
        }
    }
}

// Aggregate: out[t] = dinv[t] * (sum_e w_e * Hs[src_e] + Hs[t]) + b
// One wave per node; Hs fp16 (dinv-prescaled), fp32 accum. Edge meta per-lane,
// broadcast via readlane; unroll x8 gathers in flight.
#define RL(v, k) __builtin_amdgcn_readlane((v), (k))

template <int DOUT, bool RELU>
__global__ __launch_bounds__(256) void k_agg(const __half* __restrict__ H,
                                             const int2* __restrict__ EW,
                                             const NodeMeta* __restrict__ nm,
                                             const float* __restrict__ dinv,
                                             const float* __restrict__ bias,
                                             float* __restrict__ Out,
                                             int N, int cap) {
    int node = blockIdx.x * 4 + (threadIdx.x >> 6);
    if (node >= N) return;
    const int lane = threadIdx.x & 63;

    int c = nm[node].cnt;  // wave-uniform
    c = (c < cap) ? c : cap;

    int2 meta = make_int2(0, 0);
    if (lane < c) meta = EW[(size_t)node * cap + lane];

    float dt = dinv[node];

    if constexpr (DOUT == 128) {
        const __half2* H2 = reinterpret_cast<const __half2*>(H);
        float2 hs = __half22float2(H2[(size_t)node * 64 + lane]);
        float a0 = hs.x, a1 = hs.y;  // self term, weight 1.0
        int k = 0;
        for (; k + 8 <= c; k += 8) {
            __half2 hr[8]; float w[8];
#pragma unroll
            for (int u = 0; u < 8; u++) {
                int s = RL(meta.x, k + u);
                w[u] = __int_as_float(RL(meta.y, k + u));
                hr[u] = H2[(size_t)s * 64 + lane];
            }
#pragma unroll
            for (int u = 0; u < 8; u++) {
                float2 hv = __half22float2(hr[u]);
                a0 = fmaf(w[u], hv.x, a0);
                a1 = fmaf(w[u], hv.y, a1);
            }
        }
        for (; k + 4 <= c; k += 4) {
            __half2 hr[4]; float w[4];
#pragma unroll
            for (int u = 0; u < 4; u++) {
                int s = RL(meta.x, k + u);
                w[u] = __int_as_float(RL(meta.y, k + u));
                hr[u] = H2[(size_t)s * 64 + lane];
            }
#pragma unroll
            for (int u = 0; u < 4; u++) {
                float2 hv = __half22float2(hr[u]);
                a0 = fmaf(w[u], hv.x, a0);
                a1 = fmaf(w[u], hv.y, a1);
            }
        }
        for (; k < c; k++) {
            int s = RL(meta.x, k);
            float w = __int_as_float(RL(meta.y, k));
            float2 hv = __half22float2(H2[(size_t)s * 64 + lane]);
            a0 = fmaf(w, hv.x, a0);
            a1 = fmaf(w, hv.y, a1);
        }
        float2 b = reinterpret_cast<const float2*>(bias)[lane];
        a0 = fmaf(dt, a0, b.x);
        a1 = fmaf(dt, a1, b.y);
        if (RELU) { a0 = fmaxf(a0, 0.f); a1 = fmaxf(a1, 0.f); }
        reinterpret_cast<float2*>(Out)[(size_t)node * 64 + lane] = make_float2(a0, a1);
    } else {  // DOUT == 64
        float a = __half2float(H[(size_t)node * 64 + lane]);  // self term
        int k = 0;
        for (; k + 8 <= c; k += 8) {
            __half hr[8]; float w[8];
#pragma unroll
            for (int u = 0; u < 8; u++) {
                int s = RL(meta.x, k + u);
                w[u] = __int_as_float(RL(meta.y, k + u));
                hr[u] = H[(size_t)s * 64 + lane];
            }
#pragma unroll
            for (int u = 0; u < 8; u++) a = fmaf(w[u], __half2float(hr[u]), a);
        }
        for (; k < c; k++) {
            int s = RL(meta.x, k);
            float w = __int_as_float(RL(meta.y, k));
            a = fmaf(w, __half2float(H[(size_t)s * 64 + lane]), a);
        }
        a = fmaf(dt, a, bias[lane]);
        if (RELU) a = fmaxf(a, 0.f);
        Out[(size_t)node * 64 + lane] = a;
    }
}

extern "C" void kernel_launch(void* const* d_in, const int* in_sizes, int n_in,
                              void* d_out, int out_size, void* d_ws, size_t ws_size,
                              hipStream_t stream) {
    const int N = in_sizes[0] / 128;   // x is [N,128]
    const int E = in_sizes[2];         // edge_weight is [E]

    const float* x  = (const float*)d_in[0];
    const int*   ei = (const int*)d_in[1];   // [2,E]: row0=src, row1=dst
    const int*   src = ei;
    const int*   dst = ei + E;
    const float* ew  = (const float*)d_in[2];
    const float* W0 = (const float*)d_in[3];
    const float* b0 = (const float*)d_in[4];
    const float* W1 = (const float*)d_in[5];
    const float* b1 = (const float*)d_in[6];
    const float* W2 = (const float*)d_in[7];
    const float* b2 = (const float*)d_in[8];

    // Workspace carve; bucket capacity adapts so we never write past d_ws.
    size_t fixed = (((size_t)N * 8 + 255) & ~(size_t)255)            // nm
                 + (((size_t)N * 4 + 255) & ~(size_t)255)            // dinv
                 + (((size_t)N * 128 * 2 + 255) & ~(size_t)255)      // bufH fp16
                 + (((size_t)N * 128 * 4 + 255) & ~(size_t)255)      // bufA fp32
                 + 1024;
    int cap = 64;
    if (ws_size > fixed) {
        size_t avail = (ws_size - fixed) / ((size_t)N * 8);
        if (avail < (size_t)cap) cap = (int)avail;
    } else {
        cap = 0;
    }

    char* p = (char*)d_ws;
    auto alloc = [&](size_t bytes) -> void* {
        void* r = (void*)p;
        p += (bytes + 255) & ~(size_t)255;
        return r;
    };
    NodeMeta* nm   = (NodeMeta*)alloc((size_t)N * 8);
    float*    dinv = (float*)alloc((size_t)N * 4);
    int2*     EW   = (int2*)alloc((size_t)N * cap * 8);
    __half*   bufH = (__half*)alloc((size_t)N * 128 * 2);
    float*    bufA = (float*)alloc((size_t)N * 128 * 4);

    dim3 blk(256);
    dim3 gN((N + 255) / 256), gE((E + 255) / 256);
    dim3 gGemm((N + 127) / 128);
    dim3 gAgg((N + 3) / 4);

    // gcn_norm (restructured: dinv folded into H, EW holds raw w)
    k_init<<<gN, blk, 0, stream>>>(nm, N);
    k_build<<<gE, blk, 0, stream>>>(src, dst, ew, nm, EW, E, cap);
    k_dinv<<<gN, blk, 0, stream>>>(nm, dinv, N);

    // layer 0
    k_gemm<128><<<gGemm, blk, 0, stream>>>(x, W0, dinv, bufH, N);
    k_agg<128, true><<<gAgg, blk, 0, stream>>>(bufH, EW, nm, dinv, b0, bufA, N, cap);

    // layer 1
    k_gemm<128><<<gGemm, blk, 0, stream>>>(bufA, W1, dinv, bufH, N);
    k_agg<128, true><<<gAgg, blk, 0, stream>>>(bufH, EW, nm, dinv, b1, bufA, N, cap);

    // layer 2 (no relu)
    k_gemm<64><<<gGemm, blk, 0, stream>>>(bufA, W2, dinv, bufH, N);
    k_agg<64, false><<<gAgg, blk, 0, stream>>>(bufH, EW, nm, dinv, b2,
                                               (float*)d_out, N, cap);
}

// Round 7
// 547.742 us; speedup vs baseline: 2.1694x; 1.1161x over previous
//
#include <hip/hip_runtime.h>
#include <hip/hip_fp16.h>

// GCN 3-layer encoder for MI355X.
// dinv folded into H (Hs = dinv*h, fp16); EW packs (src<<15 | w_q15) in 4 B.
// Degree is recomputed from the bucket contents in k_dinv (wave-reduce), so
// the edge-build pass does exactly ONE atomic per edge (slot assignment).
// init(cnt=0) -> build(cnt atomic + packed EW store) -> dinv(bucket reduce)
//      -> [gemm(xW, scale dinv) -> aggregate] x3
// Workspace: cnt[N] int, dinv[N] f32, EW[N*cap] uint, bufH[N*128] fp16,
// bufA[N*128] f32. cap from ws_size (<=64).

struct alignas(8) half4 { __half2 a, b; };

#define WQ_BITS 15
#define WQ_SCALE 32768.0f
#define WQ_MASK 32767u

__global__ __launch_bounds__(256) void k_init(int* cnt, int N) {
    int i = blockIdx.x * 256 + threadIdx.x;
    if (i < N) cnt[i] = 0;
}

// One pass over edges: slot atomic + packed store. No gathers, no deg atomic.
__global__ __launch_bounds__(256) void k_build(const int* __restrict__ src,
                                               const int* __restrict__ dst,
                                               const float* __restrict__ w,
                                               int* cnt, unsigned int* __restrict__ EW,
                                               int E, int cap) {
    int e = blockIdx.x * 256 + threadIdx.x;
    if (e >= E) return;
    int s = src[e], t = dst[e];
    int wq = (int)(w[e] * WQ_SCALE + 0.5f);
    wq = (wq < (int)WQ_MASK) ? wq : (int)WQ_MASK;
    int k = atomicAdd(&cnt[t], 1);
    if (k < cap) EW[(size_t)t * cap + k] = ((unsigned int)s << WQ_BITS) | (unsigned int)wq;
}

// deg[t] = 1.0 (self-loop) + sum of bucket weights; dinv = 1/sqrt(deg).
// One wave per node: lanes read the bucket (contiguous), butterfly-reduce.
__global__ __launch_bounds__(256) void k_dinv(const int* __restrict__ cnt,
                                              const unsigned int* __restrict__ EW,
                                              float* __restrict__ dinv, int N, int cap) {
    int node = blockIdx.x * 4 + (threadIdx.x >> 6);
    if (node >= N) return;
    int lane = threadIdx.x & 63;
    int c = cnt[node];
    c = (c < cap) ? c : cap;
    float w = 0.f;
    if (lane < c) w = (float)(EW[(size_t)node * cap + lane] & WQ_MASK);
#pragma unroll
    for (int o = 32; o > 0; o >>= 1) w += __shfl_xor(w, o, 64);
    if (lane == 0) {
        float deg = 1.0f + w * (1.0f / WQ_SCALE);
        dinv[node] = 1.0f / sqrtf(deg);
    }
}

// Tiled fp32 GEMM: H[N x BN] = dinv[r] * (X[N x 128] @ W[128 x BN]), fp16 out.
// Block 256 thr: 128-row x BN-col tile, BK=16, LDS staging with register
// prefetch. Per-thread 8x(BN/16) register tile; thread rows/cols
// {4g..4g+3} u {64+4g..+3} keep ds_read_b128 2-way-bank (free).
template <int BN>
__global__ __launch_bounds__(256, 4) void k_gemm(const float* __restrict__ X,
                                                 const float* __restrict__ W,
                                                 const float* __restrict__ dinv,
                                                 __half* __restrict__ H, int N) {
    __shared__ float Xs[16][128];
    __shared__ float Ws[16][BN];

    const int tid = threadIdx.x;
    const int g = tid & 15;   // row group
    const int c = tid >> 4;   // col group
    const int rb = blockIdx.x * 128;

    const int srow = tid & 127;
    const int skh = tid >> 7;
    const size_t xrow = (size_t)((rb + srow < N) ? (rb + srow) : (N - 1));

    constexpr int CPT = BN / 16;  // cols per thread: 8 or 4

    float acc[8][CPT];
#pragma unroll
    for (int i = 0; i < 8; i++)
#pragma unroll
        for (int j = 0; j < CPT; j++) acc[i][j] = 0.f;

    float4 x0, x1, w0, w1;
    auto loadX = [&](int kb) {
        const float* p = X + xrow * 128 + kb + skh * 8;
        x0 = *(const float4*)p;
        x1 = *(const float4*)(p + 4);
    };
    auto loadW = [&](int kb) {
        if constexpr (BN == 128) {
            int wrow = tid >> 5, wcol = (tid & 31) * 4;
            w0 = *(const float4*)(W + (kb + wrow) * BN + wcol);
            w1 = *(const float4*)(W + (kb + wrow + 8) * BN + wcol);
        } else {
            int wrow = tid >> 4, wcol = (tid & 15) * 4;
            w0 = *(const float4*)(W + (kb + wrow) * BN + wcol);
        }
    };

    loadX(0);
    loadW(0);

    for (int kt = 0; kt < 8; kt++) {
        Xs[skh * 8 + 0][srow] = x0.x;
        Xs[skh * 8 + 1][srow] = x0.y;
        Xs[skh * 8 + 2][srow] = x0.z;
        Xs[skh * 8 + 3][srow] = x0.w;
        Xs[skh * 8 + 4][srow] = x1.x;
        Xs[skh * 8 + 5][srow] = x1.y;
        Xs[skh * 8 + 6][srow] = x1.z;
        Xs[skh * 8 + 7][srow] = x1.w;
        if constexpr (BN == 128) {
            int wrow = tid >> 5, wcol = (tid & 31) * 4;
            *(float4*)&Ws[wrow][wcol] = w0;
            *(float4*)&Ws[wrow + 8][wcol] = w1;
        } else {
            int wrow = tid >> 4, wcol = (tid & 15) * 4;
            *(float4*)&Ws[wrow][wcol] = w0;
        }
        __syncthreads();

        if (kt < 7) { loadX((kt + 1) * 16); loadW((kt + 1) * 16); }

#pragma unroll
        for (int k = 0; k < 16; k++) {
            float4 a0 = *(const float4*)&Xs[k][4 * g];
            float4 a1 = *(const float4*)&Xs[k][64 + 4 * g];
            float av[8] = {a0.x, a0.y, a0.z, a0.w, a1.x, a1.y, a1.z, a1.w};
            float4 b0 = *(const float4*)&Ws[k][4 * c];
            float bv[CPT];
            bv[0] = b0.x; bv[1] = b0.y; bv[2] = b0.z; bv[3] = b0.w;
            if constexpr (BN == 128) {
                float4 b1 = *(const float4*)&Ws[k][64 + 4 * c];
                bv[4] = b1.x; bv[5] = b1.y; bv[6] = b1.z; bv[7] = b1.w;
            }
#pragma unroll
            for (int i = 0; i < 8; i++)
#pragma unroll
                for (int j = 0; j < CPT; j++)
                    acc[i][j] = fmaf(av[i], bv[j], acc[i][j]);
        }
        __syncthreads();
    }

    // epilogue: scale by dinv[r], fp32 -> fp16 store.
#pragma unroll
    for (int i = 0; i < 8; i++) {
        int r = rb + ((i < 4) ? (4 * g + i) : (64 + 4 * g + i - 4));
        if (r < N) {
            float sc = dinv[r];
            half4 o0;
            o0.a = __floats2half2_rn(sc * acc[i][0], sc * acc[i][1]);
            o0.b = __floats2half2_rn(sc * acc[i][2], sc * acc[i][3]);
            *(half4*)&H[(size_t)r * BN + 4 * c] = o0;
            if constexpr (BN == 128) {
                half4 o1;
                o1.a = __floats2half2_rn(sc * acc[i][4], sc * acc[i][5]);
                o1.b = __floats2half2_rn(sc * acc[i][6], sc * acc[i][7]);
                *(half4*)&H[(size_t)r * BN + 64 + 4 * c] = o1;
            }
        }
    }
}

// Aggregate: out[t] = dinv[t] * (sum_e w_e * Hs[src_e] + Hs[t]) + b
// One wave per node; Hs fp16 (dinv-prescaled), fp32 accum. Packed edge meta
// per-lane; ONE readlane per edge, unpack (shift / and+cvt) per broadcast.
#define RL(v, k) __builtin_amdgcn_readlane((v), (k))

template <int DOUT, bool RELU>
__global__ __launch_bounds__(256) void k_agg(const __half* __restrict__ H,
                                             const unsigned int* __restrict__ EW,
                                             const int* __restrict__ cnt,
                                             const float* __restrict__ dinv,
                                             const float* __restrict__ bias,
                                             float* __restrict__ Out,
                                             int N, int cap) {
    int node = blockIdx.x * 4 + (threadIdx.x >> 6);
    if (node >= N) return;
    const int lane = threadIdx.x & 63;

    int c = cnt[node];  // wave-uniform
    c = (c < cap) ? c : cap;

    unsigned int meta = 0;
    if (lane < c) meta = EW[(size_t)node * cap + lane];

    float dt = dinv[node];

    if constexpr (DOUT == 128) {
        const __half2* H2 = reinterpret_cast<const __half2*>(H);
        float2 hs = __half22float2(H2[(size_t)node * 64 + lane]);
        float a0 = hs.x, a1 = hs.y;  // self term, weight 1.0
        int k = 0;
        for (; k + 8 <= c; k += 8) {
            __half2 hr[8]; float w[8];
#pragma unroll
            for (int u = 0; u < 8; u++) {
                unsigned int m = RL(meta, k + u);
                w[u] = (float)(m & WQ_MASK) * (1.0f / WQ_SCALE);
                hr[u] = H2[(size_t)(m >> WQ_BITS) * 64 + lane];
            }
#pragma unroll
            for (int u = 0; u < 8; u++) {
                float2 hv = __half22float2(hr[u]);
                a0 = fmaf(w[u], hv.x, a0);
                a1 = fmaf(w[u], hv.y, a1);
            }
        }
        for (; k + 4 <= c; k += 4) {
            __half2 hr[4]; float w[4];
#pragma unroll
            for (int u = 0; u < 4; u++) {
                unsigned int m = RL(meta, k + u);
                w[u] = (float)(m & WQ_MASK) * (1.0f / WQ_SCALE);
                hr[u] = H2[(size_t)(m >> WQ_BITS) * 64 + lane];
            }
#pragma unroll
            for (int u = 0; u < 4; u++) {
                float2 hv = __half22float2(hr[u]);
                a0 = fmaf(w[u], hv.x, a0);
                a1 = fmaf(w[u], hv.y, a1);
            }
        }
        for (; k < c; k++) {
            unsigned int m = RL(meta, k);
            float w = (float)(m & WQ_MASK) * (1.0f / WQ_SCALE);
            float2 hv = __half22float2(H2[(size_t)(m >> WQ_BITS) * 64 + lane]);
            a0 = fmaf(w, hv.x, a0);
            a1 = fmaf(w, hv.y, a1);
        }
        float2 b = reinterpret_cast<const float2*>(bias)[lane];
        a0 = fmaf(dt, a0, b.x);
        a1 = fmaf(dt, a1, b.y);
        if (RELU) { a0 = fmaxf(a0, 0.f); a1 = fmaxf(a1, 0.f); }
        reinterpret_cast<float2*>(Out)[(size_t)node * 64 + lane] = make_float2(a0, a1);
    } else {  // DOUT == 64
        float a = __half2float(H[(size_t)node * 64 + lane]);  // self term
        int k = 0;
        for (; k + 8 <= c; k += 8) {
            __half hr[8]; float w[8];
#pragma unroll
            for (int u = 0; u < 8; u++) {
                unsigned int m = RL(meta, k + u);
                w[u] = (float)(m & WQ_MASK) * (1.0f / WQ_SCALE);
                hr[u] = H[(size_t)(m >> WQ_BITS) * 64 + lane];
            }
#pragma unroll
            for (int u = 0; u < 8; u++) a = fmaf(w[u], __half2float(hr[u]), a);
        }
        for (; k < c; k++) {
            unsigned int m = RL(meta, k);
            float w = (float)(m & WQ_MASK) * (1.0f / WQ_SCALE);
            a = fmaf(w, __half2float(H[(size_t)(m >> WQ_BITS) * 64 + lane]), a);
        }
        a = fmaf(dt, a, bias[lane]);
        if (RELU) a = fmaxf(a, 0.f);
        Out[(size_t)node * 64 + lane] = a;
    }
}

extern "C" void kernel_launch(void* const* d_in, const int* in_sizes, int n_in,
                              void* d_out, int out_size, void* d_ws, size_t ws_size,
                              hipStream_t stream) {
    const int N = in_sizes[0] / 128;   // x is [N,128]
    const int E = in_sizes[2];         // edge_weight is [E]

    const float* x  = (const float*)d_in[0];
    const int*   ei = (const int*)d_in[1];   // [2,E]: row0=src, row1=dst
    const int*   src = ei;
    const int*   dst = ei + E;
    const float* ew  = (const float*)d_in[2];
    const float* W0 = (const float*)d_in[3];
    const float* b0 = (const float*)d_in[4];
    const float* W1 = (const float*)d_in[5];
    const float* b1 = (const float*)d_in[6];
    const float* W2 = (const float*)d_in[7];
    const float* b2 = (const float*)d_in[8];

    // Workspace carve; bucket capacity adapts so we never write past d_ws.
    size_t fixed = (((size_t)N * 4 + 255) & ~(size_t)255)            // cnt
                 + (((size_t)N * 4 + 255) & ~(size_t)255)            // dinv
                 + (((size_t)N * 128 * 2 + 255) & ~(size_t)255)      // bufH fp16
                 + (((size_t)N * 128 * 4 + 255) & ~(size_t)255)      // bufA fp32
                 + 1024;
    int cap = 64;
    if (ws_size > fixed) {
        size_t avail = (ws_size - fixed) / ((size_t)N * 4);
        if (avail < (size_t)cap) cap = (int)avail;
    } else {
        cap = 0;
    }

    char* p = (char*)d_ws;
    auto alloc = [&](size_t bytes) -> void* {
        void* r = (void*)p;
        p += (bytes + 255) & ~(size_t)255;
        return r;
    };
    int*          cnt  = (int*)alloc((size_t)N * 4);
    float*        dinv = (float*)alloc((size_t)N * 4);
    unsigned int* EW   = (unsigned int*)alloc((size_t)N * cap * 4);
    __half*       bufH = (__half*)alloc((size_t)N * 128 * 2);
    float*        bufA = (float*)alloc((size_t)N * 128 * 4);

    dim3 blk(256);
    dim3 gN((N + 255) / 256), gE((E + 255) / 256);
    dim3 gGemm((N + 127) / 128);
    dim3 gWave((N + 3) / 4);

    // gcn_norm (1 atomic/edge; deg recomputed from buckets)
    k_init<<<gN, blk, 0, stream>>>(cnt, N);
    k_build<<<gE, blk, 0, stream>>>(src, dst, ew, cnt, EW, E, cap);
    k_dinv<<<gWave, blk, 0, stream>>>(cnt, EW, dinv, N, cap);

    // layer 0
    k_gemm<128><<<gGemm, blk, 0, stream>>>(x, W0, dinv, bufH, N);
    k_agg<128, true><<<gWave, blk, 0, stream>>>(bufH, EW, cnt, dinv, b0, bufA, N, cap);

    // layer 1
    k_gemm<128><<<gGemm, blk, 0, stream>>>(bufA, W1, dinv, bufH, N);
    k_agg<128, true><<<gWave, blk, 0, stream>>>(bufH, EW, cnt, dinv, b1, bufA, N, cap);

    // layer 2 (no relu)
    k_gemm<64><<<gGemm, blk, 0, stream>>>(bufA, W2, dinv, bufH, N);
    k_agg<64, false><<<gWave, blk, 0, stream>>>(bufH, EW, cnt, dinv, b2,
                                                (float*)d_out, N, cap);
}

// Round 8
// 483.718 us; speedup vs baseline: 2.4565x; 1.1324x over previous
//
#include <hip/hip_runtime.h>
#include <hip/hip_fp16.h>

// GCN 3-layer encoder for MI355X.
// dinv folded into H (Hs = dinv*h, fp16); EW packs (src<<15 | w_q15) in 4 B;
// 1 atomic/edge build; GEMMs are f16 MFMA (16x16x32) with operand-swap so the
// epilogue stores 8 B/lane/tile; W pre-transposed to f16 scratch Wt[n][k]
// (L1/L2-resident; GEMM kernel uses no LDS at all).
// init -> wprep -> build -> dinv -> [gemm_mfma -> aggregate] x3

typedef __attribute__((ext_vector_type(8))) _Float16 f16x8;
typedef __attribute__((ext_vector_type(4))) float f32x4;

#define WQ_BITS 15
#define WQ_SCALE 32768.0f
#define WQ_MASK 32767u

__global__ __launch_bounds__(256) void k_init(int* cnt, int N) {
    int i = blockIdx.x * 256 + threadIdx.x;
    if (i < N) cnt[i] = 0;
}

// Transpose W0/W1/W2 (fp32 [k][n]) into f16 Wt [n][k]. Tiny (40960 elems).
__global__ __launch_bounds__(256) void k_wprep(const float* __restrict__ W0,
                                               const float* __restrict__ W1,
                                               const float* __restrict__ W2,
                                               __half* __restrict__ wt0,
                                               __half* __restrict__ wt1,
                                               __half* __restrict__ wt2) {
    int id = blockIdx.x * 256 + threadIdx.x;
    if (id < 16384) {
        int n = id >> 7, k = id & 127;
        wt0[id] = __float2half(W0[k * 128 + n]);
    } else if (id < 32768) {
        int j = id - 16384, n = j >> 7, k = j & 127;
        wt1[j] = __float2half(W1[k * 128 + n]);
    } else if (id < 40960) {
        int j = id - 32768, n = j >> 7, k = j & 127;  // n in [0,64)
        wt2[j] = __float2half(W2[k * 64 + n]);
    }
}

// One pass over edges: slot atomic + packed store.
__global__ __launch_bounds__(256) void k_build(const int* __restrict__ src,
                                               const int* __restrict__ dst,
                                               const float* __restrict__ w,
                                               int* cnt, unsigned int* __restrict__ EW,
                                               int E, int cap) {
    int e = blockIdx.x * 256 + threadIdx.x;
    if (e >= E) return;
    int s = src[e], t = dst[e];
    int wq = (int)(w[e] * WQ_SCALE + 0.5f);
    wq = (wq < (int)WQ_MASK) ? wq : (int)WQ_MASK;
    int k = atomicAdd(&cnt[t], 1);
    if (k < cap) EW[(size_t)t * cap + k] = ((unsigned int)s << WQ_BITS) | (unsigned int)wq;
}

// deg[t] = 1.0 + sum of bucket weights; dinv = 1/sqrt(deg). Wave per node.
__global__ __launch_bounds__(256) void k_dinv(const int* __restrict__ cnt,
                                              const unsigned int* __restrict__ EW,
                                              float* __restrict__ dinv, int N, int cap) {
    int node = blockIdx.x * 4 + (threadIdx.x >> 6);
    if (node >= N) return;
    int lane = threadIdx.x & 63;
    int c = cnt[node];
    c = (c < cap) ? c : cap;
    float w = 0.f;
    if (lane < c) w = (float)(EW[(size_t)node * cap + lane] & WQ_MASK);
#pragma unroll
    for (int o = 32; o > 0; o >>= 1) w += __shfl_xor(w, o, 64);
    if (lane == 0) {
        float deg = 1.0f + w * (1.0f / WQ_SCALE);
        dinv[node] = 1.0f / sqrtf(deg);
    }
}

// MFMA GEMM: H[N x BN] = dinv[r]*(X[N x 128] @ W[128 x BN]) as fp16.
// Per wave: 16 rows x BN cols. Operand swap: A:=W^T-frag (from Wt[n][k]),
// B:=X^T-frag -> D[r=quad*4+reg][c=lane&15] = H[row0+c][t*16+r]: each lane
// holds 4 CONSECUTIVE H-cols -> pack -> one 8 B store per tile. No LDS.
// A/B frag layout: elem[i=lane&15][k=quad*8+j] (verified m118/m120).
template <int BN, bool XFP32>
__global__ __launch_bounds__(256, 4) void k_gemm(const void* __restrict__ Xv,
                                                 const __half* __restrict__ Wt,
                                                 const float* __restrict__ dinv,
                                                 __half* __restrict__ H, int N) {
    constexpr int NT = BN / 16;  // col tiles
    const int lane = threadIdx.x & 63;
    const int wv = threadIdx.x >> 6;
    const int m = lane & 15;      // this lane's X-row within the wave tile
    const int quad = lane >> 4;
    const int row = blockIdx.x * 64 + wv * 16 + m;
    const int rowc = (row < N) ? row : (N - 1);

    // Prefetch X-frags for all 4 k-steps (k = s*32 + quad*8 + j).
    f16x8 xf[4];
    if constexpr (XFP32) {
        const float* X = (const float*)Xv;
#pragma unroll
        for (int s = 0; s < 4; s++) {
            const float4* p = (const float4*)(X + (size_t)rowc * 128 + s * 32 + quad * 8);
            float4 u0 = p[0], u1 = p[1];
            f16x8 f;
            f[0] = (_Float16)u0.x; f[1] = (_Float16)u0.y;
            f[2] = (_Float16)u0.z; f[3] = (_Float16)u0.w;
            f[4] = (_Float16)u1.x; f[5] = (_Float16)u1.y;
            f[6] = (_Float16)u1.z; f[7] = (_Float16)u1.w;
            xf[s] = f;
        }
    } else {
        const __half* X = (const __half*)Xv;
#pragma unroll
        for (int s = 0; s < 4; s++)
            xf[s] = *(const f16x8*)(X + (size_t)rowc * 128 + s * 32 + quad * 8);
    }

    f32x4 acc[NT];
#pragma unroll
    for (int t = 0; t < NT; t++) acc[t] = (f32x4){0.f, 0.f, 0.f, 0.f};

#pragma unroll
    for (int s = 0; s < 4; s++) {
#pragma unroll
        for (int t = 0; t < NT; t++) {
            // W^T frag: Wt[(t*16+m)][s*32 + quad*8 .. +7]
            f16x8 wf = *(const f16x8*)(Wt + (size_t)(t * 16 + m) * 128 + s * 32 + quad * 8);
            acc[t] = __builtin_amdgcn_mfma_f32_16x16x32_f16(wf, xf[s], acc[t], 0, 0, 0);
        }
    }

    if (row < N) {
        float sc = dinv[row];
#pragma unroll
        for (int t = 0; t < NT; t++) {
            __half2 h0 = __floats2half2_rn(sc * acc[t][0], sc * acc[t][1]);
            __half2 h1 = __floats2half2_rn(sc * acc[t][2], sc * acc[t][3]);
            __half2* dstp = (__half2*)(H + (size_t)row * BN + t * 16 + quad * 4);
            dstp[0] = h0;
            dstp[1] = h1;
        }
    }
}

// Aggregate: out[t] = dinv[t] * (sum_e w_e * Hs[src_e] + Hs[t]) + b
// Wave per node; Hs fp16 (dinv-prescaled), fp32 accum; packed meta, one
// readlane/edge. DOUT=128 writes fp16 bufA; DOUT=64 writes fp32 d_out.
#define RL(v, k) __builtin_amdgcn_readlane((v), (k))

template <int DOUT, bool RELU>
__global__ __launch_bounds__(256) void k_agg(const __half* __restrict__ H,
                                             const unsigned int* __restrict__ EW,
                                             const int* __restrict__ cnt,
                                             const float* __restrict__ dinv,
                                             const float* __restrict__ bias,
                                             void* __restrict__ Outv,
                                             int N, int cap) {
    int node = blockIdx.x * 4 + (threadIdx.x >> 6);
    if (node >= N) return;
    const int lane = threadIdx.x & 63;

    int c = cnt[node];  // wave-uniform
    c = (c < cap) ? c : cap;

    unsigned int meta = 0;
    if (lane < c) meta = EW[(size_t)node * cap + lane];

    float dt = dinv[node];

    if constexpr (DOUT == 128) {
        const __half2* H2 = reinterpret_cast<const __half2*>(H);
        float2 hs = __half22float2(H2[(size_t)node * 64 + lane]);
        float a0 = hs.x, a1 = hs.y;  // self term, weight 1.0
        int k = 0;
        for (; k + 8 <= c; k += 8) {
            __half2 hr[8]; float w[8];
#pragma unroll
            for (int u = 0; u < 8; u++) {
                unsigned int mm = RL(meta, k + u);
                w[u] = (float)(mm & WQ_MASK) * (1.0f / WQ_SCALE);
                hr[u] = H2[(size_t)(mm >> WQ_BITS) * 64 + lane];
            }
#pragma unroll
            for (int u = 0; u < 8; u++) {
                float2 hv = __half22float2(hr[u]);
                a0 = fmaf(w[u], hv.x, a0);
                a1 = fmaf(w[u], hv.y, a1);
            }
        }
        for (; k + 4 <= c; k += 4) {
            __half2 hr[4]; float w[4];
#pragma unroll
            for (int u = 0; u < 4; u++) {
                unsigned int mm = RL(meta, k + u);
                w[u] = (float)(mm & WQ_MASK) * (1.0f / WQ_SCALE);
                hr[u] = H2[(size_t)(mm >> WQ_BITS) * 64 + lane];
            }
#pragma unroll
            for (int u = 0; u < 4; u++) {
                float2 hv = __half22float2(hr[u]);
                a0 = fmaf(w[u], hv.x, a0);
                a1 = fmaf(w[u], hv.y, a1);
            }
        }
        for (; k < c; k++) {
            unsigned int mm = RL(meta, k);
            float w = (float)(mm & WQ_MASK) * (1.0f / WQ_SCALE);
            float2 hv = __half22float2(H2[(size_t)(mm >> WQ_BITS) * 64 + lane]);
            a0 = fmaf(w, hv.x, a0);
            a1 = fmaf(w, hv.y, a1);
        }
        float2 b = reinterpret_cast<const float2*>(bias)[lane];
        a0 = fmaf(dt, a0, b.x);
        a1 = fmaf(dt, a1, b.y);
        if (RELU) { a0 = fmaxf(a0, 0.f); a1 = fmaxf(a1, 0.f); }
        reinterpret_cast<__half2*>(Outv)[(size_t)node * 64 + lane] = __floats2half2_rn(a0, a1);
    } else {  // DOUT == 64, fp32 out
        float a = __half2float(H[(size_t)node * 64 + lane]);  // self term
        int k = 0;
        for (; k + 8 <= c; k += 8) {
            __half hr[8]; float w[8];
#pragma unroll
            for (int u = 0; u < 8; u++) {
                unsigned int mm = RL(meta, k + u);
                w[u] = (float)(mm & WQ_MASK) * (1.0f / WQ_SCALE);
                hr[u] = H[(size_t)(mm >> WQ_BITS) * 64 + lane];
            }
#pragma unroll
            for (int u = 0; u < 8; u++) a = fmaf(w[u], __half2float(hr[u]), a);
        }
        for (; k < c; k++) {
            unsigned int mm = RL(meta, k);
            float w = (float)(mm & WQ_MASK) * (1.0f / WQ_SCALE);
            a = fmaf(w, __half2float(H[(size_t)(mm >> WQ_BITS) * 64 + lane]), a);
        }
        a = fmaf(dt, a, bias[lane]);
        if (RELU) a = fmaxf(a, 0.f);
        ((float*)Outv)[(size_t)node * 64 + lane] = a;
    }
}

extern "C" void kernel_launch(void* const* d_in, const int* in_sizes, int n_in,
                              void* d_out, int out_size, void* d_ws, size_t ws_size,
                              hipStream_t stream) {
    const int N = in_sizes[0] / 128;   // x is [N,128]
    const int E = in_sizes[2];         // edge_weight is [E]

    const float* x  = (const float*)d_in[0];
    const int*   ei = (const int*)d_in[1];   // [2,E]: row0=src, row1=dst
    const int*   src = ei;
    const int*   dst = ei + E;
    const float* ew  = (const float*)d_in[2];
    const float* W0 = (const float*)d_in[3];
    const float* b0 = (const float*)d_in[4];
    const float* W1 = (const float*)d_in[5];
    const float* b1 = (const float*)d_in[6];
    const float* W2 = (const float*)d_in[7];
    const float* b2 = (const float*)d_in[8];

    // Workspace carve; bucket capacity adapts so we never write past d_ws.
    size_t fixed = (((size_t)N * 4 + 255) & ~(size_t)255)            // cnt
                 + (((size_t)N * 4 + 255) & ~(size_t)255)            // dinv
                 + 2 * (((size_t)N * 128 * 2 + 255) & ~(size_t)255)  // bufH, bufA fp16
                 + 3 * 33024                                         // wt0,wt1,wt2
                 + 2048;
    int cap = 64;
    if (ws_size > fixed) {
        size_t avail = (ws_size - fixed) / ((size_t)N * 4);
        if (avail < (size_t)cap) cap = (int)avail;
    } else {
        cap = 0;
    }

    char* p = (char*)d_ws;
    auto alloc = [&](size_t bytes) -> void* {
        void* r = (void*)p;
        p += (bytes + 255) & ~(size_t)255;
        return r;
    };
    int*          cnt  = (int*)alloc((size_t)N * 4);
    float*        dinv = (float*)alloc((size_t)N * 4);
    unsigned int* EW   = (unsigned int*)alloc((size_t)N * cap * 4);
    __half*       bufH = (__half*)alloc((size_t)N * 128 * 2);
    __half*       bufA = (__half*)alloc((size_t)N * 128 * 2);
    __half*       wt0  = (__half*)alloc(16384 * 2);
    __half*       wt1  = (__half*)alloc(16384 * 2);
    __half*       wt2  = (__half*)alloc(8192 * 2);

    dim3 blk(256);
    dim3 gN((N + 255) / 256), gE((E + 255) / 256);
    dim3 gGemm((N + 63) / 64);
    dim3 gWave((N + 3) / 4);

    // gcn_norm + weight prep
    k_init<<<gN, blk, 0, stream>>>(cnt, N);
    k_wprep<<<160, blk, 0, stream>>>(W0, W1, W2, wt0, wt1, wt2);
    k_build<<<gE, blk, 0, stream>>>(src, dst, ew, cnt, EW, E, cap);
    k_dinv<<<gWave, blk, 0, stream>>>(cnt, EW, dinv, N, cap);

    // layer 0 (x fp32 -> cvt in-kernel)
    k_gemm<128, true><<<gGemm, blk, 0, stream>>>(x, wt0, dinv, bufH, N);
    k_agg<128, true><<<gWave, blk, 0, stream>>>(bufH, EW, cnt, dinv, b0, bufA, N, cap);

    // layer 1
    k_gemm<128, false><<<gGemm, blk, 0, stream>>>(bufA, wt1, dinv, bufH, N);
    k_agg<128, true><<<gWave, blk, 0, stream>>>(bufH, EW, cnt, dinv, b1, bufA, N, cap);

    // layer 2 (no relu, fp32 out)
    k_gemm<64, false><<<gGemm, blk, 0, stream>>>(bufA, wt2, dinv, bufH, N);
    k_agg<64, false><<<gWave, blk, 0, stream>>>(bufH, EW, cnt, dinv, b2,
                                                d_out, N, cap);
}

// Round 9
// 448.155 us; speedup vs baseline: 2.6514x; 1.0794x over previous
//
#include <hip/hip_runtime.h>
#include <hip/hip_fp16.h>

// GCN 3-layer encoder for MI355X.
// dinv folded into H (Hs = dinv*h, fp16); EW packs (src<<15 | w_q15) in 4 B;
// build does 1 atomic/edge and is XCD-PARTITIONED: partition p=(dst>>4)&7 is
// handled only by blocks with blockIdx&7==p (round-robin -> same XCD), so
// each cnt/EW line dirties exactly one L2 copy (kills the 8x writeback amp).
// dinv is computed inside gemm0 (per-block bucket reduce) - no k_dinv pass.
// k_pre(init+wprep) -> k_build -> [gemm_mfma(+dinv) -> aggregate] x3

typedef __attribute__((ext_vector_type(8))) _Float16 f16x8;
typedef __attribute__((ext_vector_type(4))) float f32x4;

#define WQ_BITS 15
#define WQ_SCALE 32768.0f
#define WQ_MASK 32767u

// Fused: zero cnt + transpose W0/W1/W2 (fp32 [k][n]) into f16 Wt [n][k].
__global__ __launch_bounds__(256) void k_pre(int* cnt, int N,
                                             const float* __restrict__ W0,
                                             const float* __restrict__ W1,
                                             const float* __restrict__ W2,
                                             __half* __restrict__ wt0,
                                             __half* __restrict__ wt1,
                                             __half* __restrict__ wt2) {
    int id = blockIdx.x * 256 + threadIdx.x;
    if (id < N) cnt[id] = 0;
    if (id < 16384) {
        int n = id >> 7, k = id & 127;
        wt0[id] = __float2half(W0[k * 128 + n]);
    } else if (id < 32768) {
        int j = id - 16384, n = j >> 7, k = j & 127;
        wt1[j] = __float2half(W1[k * 128 + n]);
    } else if (id < 40960) {
        int j = id - 32768, n = j >> 7, k = j & 127;  // n in [0,64)
        wt2[j] = __float2half(W2[k * 64 + n]);
    }
}

// XCD-partitioned edge build: block handles partition p = blockIdx&7; scans
// its chunk slice, processes only edges with (dst>>4)&7 == p. Correctness
// does not depend on block->XCD mapping (device-scope atomic); locality does.
__global__ __launch_bounds__(256) void k_build(const int* __restrict__ src,
                                               const int* __restrict__ dst,
                                               const float* __restrict__ w,
                                               int* cnt, unsigned int* __restrict__ EW,
                                               int E, int cap) {
    const int p = blockIdx.x & 7;
    const int chunk = blockIdx.x >> 3;
    const int nchunk = gridDim.x >> 3;
    const int stride = nchunk * 256;
    for (int e = chunk * 256 + threadIdx.x; e < E; e += stride) {
        int t = dst[e];
        if (((t >> 4) & 7) != p) continue;
        int s = src[e];
        int wq = (int)(w[e] * WQ_SCALE + 0.5f);
        wq = (wq < (int)WQ_MASK) ? wq : (int)WQ_MASK;
        int k = atomicAdd(&cnt[t], 1);
        if (k < cap) EW[(size_t)t * cap + k] = ((unsigned int)s << WQ_BITS) | (unsigned int)wq;
    }
}

// MFMA GEMM: H[N x BN] = dinv[r]*(X[N x 128] @ W[128 x BN]) as fp16.
// Per wave: 16 rows x BN cols. Operand swap: A:=W^T-frag (from Wt[n][k]),
// B:=X^T-frag -> each lane holds 4 consecutive H-cols -> 8 B stores. No LDS
// in the main path. DINV=true (layer 0): block computes dinv for its own 64
// rows from the buckets (4 thr/row, shfl reduce), stores to LDS + global.
template <int BN, bool XFP32, bool DINV>
__global__ __launch_bounds__(256, 4) void k_gemm(const void* __restrict__ Xv,
                                                 const __half* __restrict__ Wt,
                                                 float* __restrict__ dinv,
                                                 const int* __restrict__ cnt,
                                                 const unsigned int* __restrict__ EW,
                                                 int cap,
                                                 __half* __restrict__ H, int N) {
    __shared__ float dinv_s[64];
    const int tid = threadIdx.x;
    const int lane = tid & 63;
    const int wv = tid >> 6;
    const int m = lane & 15;
    const int quad = lane >> 4;
    const int rb = blockIdx.x * 64;
    const int row = rb + wv * 16 + m;
    const int rowc = (row < N) ? row : (N - 1);

    if constexpr (DINV) {
        // 4 threads per row; slots strided by 4; reduce via shfl_xor(1,2).
        int rloc = tid >> 2, sub = tid & 3;
        int r = rb + rloc;
        float wsum = 0.f;
        if (r < N) {
            int c = cnt[r];
            c = (c < cap) ? c : cap;
            for (int j = sub; j < c; j += 4)
                wsum += (float)(EW[(size_t)r * cap + j] & WQ_MASK);
        }
        wsum += __shfl_xor(wsum, 1, 64);
        wsum += __shfl_xor(wsum, 2, 64);
        float dv = 1.0f / sqrtf(1.0f + wsum * (1.0f / WQ_SCALE));
        if (sub == 0) {
            dinv_s[rloc] = dv;
            if (r < N) dinv[r] = dv;
        }
        __syncthreads();
    }

    // Prefetch X-frags for all 4 k-steps (k = s*32 + quad*8 + j).
    f16x8 xf[4];
    if constexpr (XFP32) {
        const float* X = (const float*)Xv;
#pragma unroll
        for (int s = 0; s < 4; s++) {
            const float4* p = (const float4*)(X + (size_t)rowc * 128 + s * 32 + quad * 8);
            float4 u0 = p[0], u1 = p[1];
            f16x8 f;
            f[0] = (_Float16)u0.x; f[1] = (_Float16)u0.y;
            f[2] = (_Float16)u0.z; f[3] = (_Float16)u0.w;
            f[4] = (_Float16)u1.x; f[5] = (_Float16)u1.y;
            f[6] = (_Float16)u1.z; f[7] = (_Float16)u1.w;
            xf[s] = f;
        }
    } else {
        const __half* X = (const __half*)Xv;
#pragma unroll
        for (int s = 0; s < 4; s++)
            xf[s] = *(const f16x8*)(X + (size_t)rowc * 128 + s * 32 + quad * 8);
    }

    constexpr int NT = BN / 16;
    f32x4 acc[NT];
#pragma unroll
    for (int t = 0; t < NT; t++) acc[t] = (f32x4){0.f, 0.f, 0.f, 0.f};

#pragma unroll
    for (int s = 0; s < 4; s++) {
#pragma unroll
        for (int t = 0; t < NT; t++) {
            f16x8 wf = *(const f16x8*)(Wt + (size_t)(t * 16 + m) * 128 + s * 32 + quad * 8);
            acc[t] = __builtin_amdgcn_mfma_f32_16x16x32_f16(wf, xf[s], acc[t], 0, 0, 0);
        }
    }

    if (row < N) {
        float sc = DINV ? dinv_s[wv * 16 + m] : dinv[row];
#pragma unroll
        for (int t = 0; t < NT; t++) {
            __half2 h0 = __floats2half2_rn(sc * acc[t][0], sc * acc[t][1]);
            __half2 h1 = __floats2half2_rn(sc * acc[t][2], sc * acc[t][3]);
            __half2* dstp = (__half2*)(H + (size_t)row * BN + t * 16 + quad * 4);
            dstp[0] = h0;
            dstp[1] = h1;
        }
    }
}

// Aggregate: out[t] = dinv[t] * (sum_e w_e * Hs[src_e] + Hs[t]) + b
// Wave per node; Hs fp16 (dinv-prescaled), fp32 accum; packed meta, one
// readlane/edge. DOUT=128 writes fp16 bufA; DOUT=64 writes fp32 d_out.
#define RL(v, k) __builtin_amdgcn_readlane((v), (k))

template <int DOUT, bool RELU>
__global__ __launch_bounds__(256) void k_agg(const __half* __restrict__ H,
                                             const unsigned int* __restrict__ EW,
                                             const int* __restrict__ cnt,
                                             const float* __restrict__ dinv,
                                             const float* __restrict__ bias,
                                             void* __restrict__ Outv,
                                             int N, int cap) {
    int node = blockIdx.x * 4 + (threadIdx.x >> 6);
    if (node >= N) return;
    const int lane = threadIdx.x & 63;

    int c = cnt[node];  // wave-uniform
    c = (c < cap) ? c : cap;

    unsigned int meta = 0;
    if (lane < c) meta = EW[(size_t)node * cap + lane];

    float dt = dinv[node];

    if constexpr (DOUT == 128) {
        const __half2* H2 = reinterpret_cast<const __half2*>(H);
        float2 hs = __half22float2(H2[(size_t)node * 64 + lane]);
        float a0 = hs.x, a1 = hs.y;  // self term, weight 1.0
        int k = 0;
        for (; k + 8 <= c; k += 8) {
            __half2 hr[8]; float w[8];
#pragma unroll
            for (int u = 0; u < 8; u++) {
                unsigned int mm = RL(meta, k + u);
                w[u] = (float)(mm & WQ_MASK) * (1.0f / WQ_SCALE);
                hr[u] = H2[(size_t)(mm >> WQ_BITS) * 64 + lane];
            }
#pragma unroll
            for (int u = 0; u < 8; u++) {
                float2 hv = __half22float2(hr[u]);
                a0 = fmaf(w[u], hv.x, a0);
                a1 = fmaf(w[u], hv.y, a1);
            }
        }
        for (; k + 4 <= c; k += 4) {
            __half2 hr[4]; float w[4];
#pragma unroll
            for (int u = 0; u < 4; u++) {
                unsigned int mm = RL(meta, k + u);
                w[u] = (float)(mm & WQ_MASK) * (1.0f / WQ_SCALE);
                hr[u] = H2[(size_t)(mm >> WQ_BITS) * 64 + lane];
            }
#pragma unroll
            for (int u = 0; u < 4; u++) {
                float2 hv = __half22float2(hr[u]);
                a0 = fmaf(w[u], hv.x, a0);
                a1 = fmaf(w[u], hv.y, a1);
            }
        }
        for (; k < c; k++) {
            unsigned int mm = RL(meta, k);
            float w = (float)(mm & WQ_MASK) * (1.0f / WQ_SCALE);
            float2 hv = __half22float2(H2[(size_t)(mm >> WQ_BITS) * 64 + lane]);
            a0 = fmaf(w, hv.x, a0);
            a1 = fmaf(w, hv.y, a1);
        }
        float2 b = reinterpret_cast<const float2*>(bias)[lane];
        a0 = fmaf(dt, a0, b.x);
        a1 = fmaf(dt, a1, b.y);
        if (RELU) { a0 = fmaxf(a0, 0.f); a1 = fmaxf(a1, 0.f); }
        reinterpret_cast<__half2*>(Outv)[(size_t)node * 64 + lane] = __floats2half2_rn(a0, a1);
    } else {  // DOUT == 64, fp32 out
        float a = __half2float(H[(size_t)node * 64 + lane]);  // self term
        int k = 0;
        for (; k + 8 <= c; k += 8) {
            __half hr[8]; float w[8];
#pragma unroll
            for (int u = 0; u < 8; u++) {
                unsigned int mm = RL(meta, k + u);
                w[u] = (float)(mm & WQ_MASK) * (1.0f / WQ_SCALE);
                hr[u] = H[(size_t)(mm >> WQ_BITS) * 64 + lane];
            }
#pragma unroll
            for (int u = 0; u < 8; u++) a = fmaf(w[u], __half2float(hr[u]), a);
        }
        for (; k < c; k++) {
            unsigned int mm = RL(meta, k);
            float w = (float)(mm & WQ_MASK) * (1.0f / WQ_SCALE);
            a = fmaf(w, __half2float(H[(size_t)(mm >> WQ_BITS) * 64 + lane]), a);
        }
        a = fmaf(dt, a, bias[lane]);
        if (RELU) a = fmaxf(a, 0.f);
        ((float*)Outv)[(size_t)node * 64 + lane] = a;
    }
}

extern "C" void kernel_launch(void* const* d_in, const int* in_sizes, int n_in,
                              void* d_out, int out_size, void* d_ws, size_t ws_size,
                              hipStream_t stream) {
    const int N = in_sizes[0] / 128;   // x is [N,128]
    const int E = in_sizes[2];         // edge_weight is [E]

    const float* x  = (const float*)d_in[0];
    const int*   ei = (const int*)d_in[1];   // [2,E]: row0=src, row1=dst
    const int*   src = ei;
    const int*   dst = ei + E;
    const float* ew  = (const float*)d_in[2];
    const float* W0 = (const float*)d_in[3];
    const float* b0 = (const float*)d_in[4];
    const float* W1 = (const float*)d_in[5];
    const float* b1 = (const float*)d_in[6];
    const float* W2 = (const float*)d_in[7];
    const float* b2 = (const float*)d_in[8];

    // Workspace carve; bucket capacity adapts so we never write past d_ws.
    size_t fixed = (((size_t)N * 4 + 255) & ~(size_t)255)            // cnt
                 + (((size_t)N * 4 + 255) & ~(size_t)255)            // dinv
                 + 2 * (((size_t)N * 128 * 2 + 255) & ~(size_t)255)  // bufH, bufA fp16
                 + 3 * 33024                                         // wt0,wt1,wt2
                 + 2048;
    int cap = 64;
    if (ws_size > fixed) {
        size_t avail = (ws_size - fixed) / ((size_t)N * 4);
        if (avail < (size_t)cap) cap = (int)avail;
    } else {
        cap = 0;
    }

    char* p = (char*)d_ws;
    auto alloc = [&](size_t bytes) -> void* {
        void* r = (void*)p;
        p += (bytes + 255) & ~(size_t)255;
        return r;
    };
    int*          cnt  = (int*)alloc((size_t)N * 4);
    float*        dinv = (float*)alloc((size_t)N * 4);
    unsigned int* EW   = (unsigned int*)alloc((size_t)N * cap * 4);
    __half*       bufH = (__half*)alloc((size_t)N * 128 * 2);
    __half*       bufA = (__half*)alloc((size_t)N * 128 * 2);
    __half*       wt0  = (__half*)alloc(16384 * 2);
    __half*       wt1  = (__half*)alloc(16384 * 2);
    __half*       wt2  = (__half*)alloc(8192 * 2);

    dim3 blk(256);
    int preN = (N > 40960) ? N : 40960;
    dim3 gPre((preN + 255) / 256);
    dim3 gBuild(6656);  // 8 partitions x 832 chunks
    dim3 gGemm((N + 63) / 64);
    dim3 gWave((N + 3) / 4);

    k_pre<<<gPre, blk, 0, stream>>>(cnt, N, W0, W1, W2, wt0, wt1, wt2);
    k_build<<<gBuild, blk, 0, stream>>>(src, dst, ew, cnt, EW, E, cap);

    // layer 0 (x fp32 -> cvt in-kernel; dinv computed in-block)
    k_gemm<128, true, true><<<gGemm, blk, 0, stream>>>(x, wt0, dinv, cnt, EW, cap, bufH, N);
    k_agg<128, true><<<gWave, blk, 0, stream>>>(bufH, EW, cnt, dinv, b0, bufA, N, cap);

    // layer 1
    k_gemm<128, false, false><<<gGemm, blk, 0, stream>>>(bufA, wt1, dinv, cnt, EW, cap, bufH, N);
    k_agg<128, true><<<gWave, blk, 0, stream>>>(bufH, EW, cnt, dinv, b1, bufA, N, cap);

    // layer 2 (no relu, fp32 out)
    k_gemm<64, false, false><<<gGemm, blk, 0, stream>>>(bufA, wt2, dinv, cnt, EW, cap, bufH, N);
    k_agg<64, false><<<gWave, blk, 0, stream>>>(bufH, EW, cnt, dinv, b2,
                                                d_out, N, cap);
}